// Round 5
// baseline (10855.119 us; speedup 1.0000x reference)
//
#include <hip/hip_runtime.h>
#include <math.h>

#define NN 4096
#define EE 65536
#define H 128
#define NF 4
#define MNODE 8
#define MEDGE 4
#define NT 2
#define NBLK 256

// All device pointers for the mega-kernel (passed by value, <4KB).
struct KArgs {
  const float *F0, *mesh_node, *mesh_edge, *Wm, *bm, *Wd0, *bd0, *Wd, *bd,
              *pool_w, *Wu, *bu, *Wout, *bout;
  const int* ei;
  float* out;
  int *bar, *cnt, *rp, *cursor, *cols, *permb, *rankb;
  float *svb;
  unsigned long long* keys;
  float *score, *dinv2, *dinv1, *pwn, *S, *P, *Q, *h1, *hbuf, *tsb;
  float *x0, *x1, *x2, *x3, *x4, *xcur;
  float *A820, *A164, *A33, *A7, *A2b;
  float *dv820, *dv164, *dv33, *dv7, *dv2;
  float *ts2, *Fcur;
};

// Device-scope grid barrier. Requires all NBLK blocks resident (1 block/CU at
// grid=256). Release: syncthreads drains block's vmem (compiler emits
// s_waitcnt vmcnt(0) before s_barrier), leader's threadfence writes back its
// XCD L2. Acquire: leader's threadfence invalidates L1/L2 after gen bump.
__device__ __forceinline__ void gbar(int* bar) {
  __syncthreads();
  if (threadIdx.x == 0) {
    __threadfence();
    int g = __hip_atomic_load(bar + 1, __ATOMIC_RELAXED, __HIP_MEMORY_SCOPE_AGENT);
    int v = __hip_atomic_fetch_add(bar, 1, __ATOMIC_ACQ_REL, __HIP_MEMORY_SCOPE_AGENT);
    if (v == NBLK - 1) {
      __hip_atomic_store(bar, 0, __ATOMIC_RELAXED, __HIP_MEMORY_SCOPE_AGENT);
      __hip_atomic_fetch_add(bar + 1, 1, __ATOMIC_RELEASE, __HIP_MEMORY_SCOPE_AGENT);
    } else {
      long long spins = 0;
      while (__hip_atomic_load(bar + 1, __ATOMIC_ACQUIRE, __HIP_MEMORY_SCOPE_AGENT) == g) {
        if (++spins > (1LL << 20)) break;  // failsafe: wrong-answer beats hang
        __builtin_amdgcn_s_sleep(1);
      }
    }
    __threadfence();
  }
  __syncthreads();
}

// exact jax.lax.top_k rank: block bid owns 16 i's; 16 j-slices per i.
__device__ __forceinline__ void toprank_ph(unsigned long long* smem,
    const unsigned long long* keys, const float* score, int n, int k,
    int* perm, float* sv, int* rank) {
  int bid = blockIdx.x, tid = threadIdx.x;
  if (bid * 16 < n) {
    unsigned long long* kls = smem;
    int* red = (int*)(smem + 4096);
    for (int j = tid; j < n; j += 256) kls[j] = keys[j];
    __syncthreads();
    int ii = tid >> 4, jj = tid & 15;
    int i = bid * 16 + ii;
    unsigned long long ki = (i < n) ? kls[i] : ~0ULL;
    int r = 0;
    for (int j = jj; j < n; j += 16) r += (kls[j] > ki) ? 1 : 0;
    red[tid] = r;
    __syncthreads();
    for (int off = 8; off > 0; off >>= 1) {
      if (jj < off) red[tid] += red[tid + off];
      __syncthreads();
    }
    if (jj == 0 && i < n) {
      int rr = red[tid];
      rank[i] = rr;
      if (rr < k) { perm[rr] = i; sv[rr] = score[i]; }
    }
    __syncthreads();
  }
}

// A820[r,c] = (A1@A1)[perm_r,perm_c] via CSR scatter into LDS; dv fused.
__device__ __forceinline__ void a820_ph(unsigned long long* smem, const int* rp,
    const int* cols, const int* perm, float* A820, float* dv) {
  int bid = blockIdx.x, tid = threadIdx.x;
  float* acc = (float*)smem;
  float* red = acc + 4096;
  for (int r = bid; r < 820; r += NBLK) {
    __syncthreads();
    for (int i2 = tid; i2 < NN; i2 += 256) acc[i2] = 0.f;
    __syncthreads();
    int pi = perm[r];
    int beg = rp[pi], end = rp[pi + 1];
    for (int e = beg + tid; e < end; e += 256) {
      int c = cols[e];
      if (c != pi) atomicAdd(&acc[c], 1.f);
    }
    if (tid == 0) atomicAdd(&acc[pi], 1.f);
    for (int e0 = beg; e0 < end; e0++) {
      int c = cols[e0];
      if (c == pi) continue;
      int b2 = rp[c], e2 = rp[c + 1];
      for (int e = b2 + tid; e < e2; e += 256) {
        int c2 = cols[e];
        if (c2 != c) atomicAdd(&acc[c2], 1.f);
      }
      if (tid == 0) atomicAdd(&acc[c], 1.f);
    }
    __syncthreads();
    float ps = 0.f;
    for (int cc = tid; cc < 820; cc += 256) {
      float v = (cc == r) ? 0.f : acc[perm[cc]];
      A820[(size_t)r * 820 + cc] = v;
      ps += v;
    }
    red[tid] = ps;
    __syncthreads();
    for (int off = 128; off > 0; off >>= 1) {
      if (tid < off) red[tid] += red[tid + off];
      __syncthreads();
    }
    if (tid == 0) dv[r] = 1.f / sqrtf(red[0] + 2.f);
  }
}

// augment+pool row-major: compact nonzeros of A[pr,:] into LDS, gather in-row.
// Values are exact small ints -> order-independent exact sums.
__device__ __forceinline__ void augpool_ph(unsigned long long* smem, const float* Ap,
    int np, const int* perm, int kn, float* Aout, float* dvout) {
  int bid = blockIdx.x, tid = threadIdx.x;
  float* sf = (float*)smem;
  float* rowv = sf;
  int* rowi = (int*)(sf + 832);
  int* pcs = (int*)(sf + 1664);
  int* nnzp = (int*)(sf + 1860);
  float* red = sf + 1872;
  for (int r = bid; r < kn; r += NBLK) {
    __syncthreads();
    if (tid == 0) *nnzp = 0;
    for (int c = tid; c < kn; c += 256) pcs[c] = perm[c];
    __syncthreads();
    int pr = perm[r];
    for (int i2 = tid; i2 < np; i2 += 256) {
      float v = Ap[(size_t)pr * np + i2];
      if (v != 0.f) { int pos = atomicAdd(nnzp, 1); rowv[pos] = v; rowi[pos] = i2; }
    }
    __syncthreads();
    int nnz = *nnzp;
    int pc = (tid < kn) ? pcs[tid] : 0;
    float accv = 0.f;
    for (int e = 0; e < nnz; e++) accv += rowv[e] * Ap[(size_t)rowi[e] * np + pc];
    float v = 0.f;
    if (tid < kn) {
      v = (tid == r) ? 0.f : (accv + 2.f * Ap[(size_t)pr * np + pc]);
      Aout[(size_t)r * kn + tid] = v;
    }
    red[tid] = v;
    __syncthreads();
    for (int off = 128; off > 0; off >>= 1) {
      if (tid < off) red[tid] += red[tid + off];
      __syncthreads();
    }
    if (tid == 0) dvout[r] = 1.f / sqrtf(red[0] + 2.f);
  }
}

// ts[r] = dv[r]*sv[r]*(x[perm[r]] @ W); 8 rows per 128-thread half.
__device__ __forceinline__ void mmW_ph(const float* x, const float* W, int k,
    const float* dv, const float* sv, const int* perm, float* outts) {
  int bid = blockIdx.x, tid = threadIdx.x;
  int half = tid >> 7, t = tid & 127;
  for (int g = bid; g * 16 < k; g += NBLK) {
    int rbase = g * 16 + half * 8;
    float acc[8] = {};
    int prs[8]; float scl[8];
#pragma unroll
    for (int j = 0; j < 8; j++) {
      int row = rbase + j;
      int rv = (row < k) ? row : (k - 1);
      prs[j] = perm[rv];
      scl[j] = dv[rv] * sv[rv];
    }
#pragma unroll 2
    for (int kk = 0; kk < H; kk++) {
      float b = W[kk * H + t];
#pragma unroll
      for (int j = 0; j < 8; j++) acc[j] += x[(size_t)prs[j] * H + kk] * b;
    }
#pragma unroll
    for (int j = 0; j < 8; j++) {
      int row = rbase + j;
      if (row < k) outts[(size_t)row * H + t] = acc[j] * scl[j];
    }
  }
}

// branch-free dense GCN: out = dv*(A@ts + 2ts)+b (+relu), optional score/keys.
__device__ __forceinline__ void dgcn_ph(unsigned long long* smem, const float* A, int n,
    const float* ts, const float* dv, const float* bias, int relu, float* outx,
    int lvl, const float* pw, const float* pwn, float* score, unsigned long long* keys) {
  int bid = blockIdx.x, tid = threadIdx.x;
  int half = tid >> 7, t = tid & 127, wv = (tid >> 6) & 1, lane = tid & 63;
  float* wred = (float*)smem;  // 32 floats
  for (int g = bid; g * 16 < n; g += NBLK) {
    int rbase = g * 16 + half * 8;
    int rws[8];
#pragma unroll
    for (int j = 0; j < 8; j++) { int row = rbase + j; rws[j] = (row < n) ? row : (n - 1); }
    float acc[8] = {};
#pragma unroll 4
    for (int kk = 0; kk < n; kk++) {
      float b = ts[(size_t)kk * H + t];
#pragma unroll
      for (int j = 0; j < 8; j++) acc[j] += A[(size_t)rws[j] * n + kk] * b;
    }
    float vj[8];
#pragma unroll
    for (int j = 0; j < 8; j++) {
      float v = dv[rws[j]] * (acc[j] + 2.f * ts[(size_t)rws[j] * H + t]) + bias[t];
      if (relu) v = fmaxf(v, 0.f);
      vj[j] = v;
      if (rbase + j < n) outx[(size_t)(rbase + j) * H + t] = v;
    }
    if (lvl >= 0) {
      __syncthreads();
#pragma unroll
      for (int j = 0; j < 8; j++) {
        float s = vj[j] * pw[t];
#pragma unroll
        for (int off = 32; off > 0; off >>= 1) s += __shfl_down(s, off);
        if (lane == 0) wred[(half * 2 + wv) * 8 + j] = s;
      }
      __syncthreads();
      if (t == 0) {
#pragma unroll
        for (int j = 0; j < 8; j++) {
          int row = rbase + j;
          if (row < n) {
            float s = wred[(half * 2) * 8 + j] + wred[(half * 2 + 1) * 8 + j];
            s = tanhf(s / pwn[lvl]);
            score[row] = s;
            unsigned u = __float_as_uint(s + 0.0f);
            u ^= ((unsigned)((int)u >> 31)) | 0x80000000u;
            keys[row] = ((unsigned long long)u << 12) | (unsigned)(4095 - row);
          }
        }
      }
      __syncthreads();
    }
  }
}

// ts[row] = dv[row]*((res[row] + (rank<k ? xc[rank] : 0)) @ W)
__device__ __forceinline__ void upmm_ph(const float* res, const int* rankl, int k,
    const float* xc, const float* W, const float* dv, float* outts, int n) {
  int bid = blockIdx.x, tid = threadIdx.x;
  int half = tid >> 7, t = tid & 127;
  for (int g = bid; g * 16 < n; g += NBLK) {
    int rbase = g * 16 + half * 8;
    float acc[8] = {};
    int rr[8]; float scl[8], dvv[8]; const float* up[8];
#pragma unroll
    for (int j = 0; j < 8; j++) {
      int row = rbase + j;
      int rv = (row < n) ? row : (n - 1);
      rr[j] = rv;
      int rnk = rankl[rv];
      int kept = rnk < k;
      up[j] = xc + (size_t)(kept ? rnk : 0) * H;
      scl[j] = kept ? 1.f : 0.f;
      dvv[j] = dv[rv];
    }
#pragma unroll 2
    for (int kk = 0; kk < H; kk++) {
      float b = W[kk * H + t];
#pragma unroll
      for (int j = 0; j < 8; j++) {
        float av = res[(size_t)rr[j] * H + kk] + scl[j] * up[j][kk];
        acc[j] += av * b;
      }
    }
#pragma unroll
    for (int j = 0; j < 8; j++) {
      int row = rbase + j;
      if (row < n) outts[(size_t)row * H + t] = acc[j] * dvv[j];
    }
  }
}

__global__ __launch_bounds__(256, 1) void mega(KArgs a) {
  __shared__ unsigned long long smem[4352];  // 34 KB, overlaid per phase
  const int bid = blockIdx.x, tid = threadIdx.x;
  float* sf = (float*)smem;
  int* si = (int*)smem;
  const int half = tid >> 7, t = tid & 127;
  const int wv = (tid >> 6) & 1, lane = tid & 63;

  // ---- S0: edge count + segment-sum(mesh_edge) + pool_w norms ----
  {
    int e = bid * 256 + tid;  // EE == 256*256 exactly
    int d = a.ei[EE + e];
    atomicAdd(&a.cnt[d], 1);
#pragma unroll
    for (int m = 0; m < MEDGE; m++) atomicAdd(&a.S[d * 4 + m], a.mesh_edge[e * 4 + m]);
    if (bid < 5) {
      float v = (tid < 128) ? a.pool_w[bid * H + tid] : 0.f;
      sf[tid] = v * v;
      __syncthreads();
      for (int off = 128; off > 0; off >>= 1) {
        if (tid < off) sf[tid] += sf[tid + off];
        __syncthreads();
      }
      if (tid == 0) a.pwn[bid] = sqrtf(sf[0]);
    }
  }
  gbar(a.bar);
  // ---- S1: exclusive scan (block 0) + dinv (blocks 1..16) ----
  if (bid == 0) {
    int base_j = tid * 16;
    int vals[16]; int tot = 0;
#pragma unroll
    for (int m = 0; m < 16; m++) { vals[m] = tot; tot += a.cnt[base_j + m]; }
    si[tid] = tot;
    __syncthreads();
    for (int off = 1; off < 256; off <<= 1) {
      int add = (tid >= off) ? si[tid - off] : 0;
      __syncthreads();
      si[tid] += add;
      __syncthreads();
    }
    int base = si[tid] - tot;
#pragma unroll
    for (int m = 0; m < 16; m++) {
      int rpv = base + vals[m];
      a.rp[base_j + m] = rpv;
      a.cursor[base_j + m] = rpv;
    }
    if (tid == 255) a.rp[NN] = si[255];
  } else if (bid <= 16) {
    int i = (bid - 1) * 256 + tid;
    float c = (float)a.cnt[i];
    a.dinv2[i] = 1.f / sqrtf(c + 2.f);
    a.dinv1[i] = 1.f / sqrtf(c + 1.f);
  }
  gbar(a.bar);
  // ---- S2: CSR fill ----
  {
    int e = bid * 256 + tid;
    int d = a.ei[EE + e], s0 = a.ei[e];
    int pos = atomicAdd(&a.cursor[d], 1);
    a.cols[pos] = s0;
  }
  gbar(a.bar);

  const int KL[5] = {820, 164, 33, 7, 2};
  const int SZ[5] = {4096, 820, 164, 33, 7};
  float* Aarr[5] = {a.A820, a.A164, a.A33, a.A7, a.A2b};
  float* dvarr[5] = {a.dv820, a.dv164, a.dv33, a.dv7, a.dv2};
  float* xs[5] = {a.x0, a.x1, a.x2, a.x3, a.x4};

  for (int step = 0; step < NT; step++) {
    const float* Fsrc = step ? a.Fcur : a.F0;
    // ---- PA: P = na@Wm[0:140], Q = na@Wm[140:280] ----
    {
      int g = bid * 2 + half;  // 512 groups of 8 rows
      int row0 = g * 8;
      float accP[8] = {}, accQ[8] = {};
#pragma unroll
      for (int kk = 0; kk < NF; kk++) {
        float b1 = a.Wm[kk * H + t], b2 = a.Wm[(140 + kk) * H + t];
#pragma unroll
        for (int r = 0; r < 8; r++) {
          float av = Fsrc[(row0 + r) * NF + kk];
          accP[r] += av * b1; accQ[r] += av * b2;
        }
      }
#pragma unroll
      for (int kk = 0; kk < MNODE; kk++) {
        float b1 = a.Wm[(NF + kk) * H + t], b2 = a.Wm[(140 + NF + kk) * H + t];
#pragma unroll
        for (int r = 0; r < 8; r++) {
          float av = a.mesh_node[(row0 + r) * MNODE + kk];
          accP[r] += av * b1; accQ[r] += av * b2;
        }
      }
#pragma unroll 2
      for (int kk = 0; kk < H; kk++) {
        float b1 = a.Wm[(12 + kk) * H + t], b2 = a.Wm[(152 + kk) * H + t];
#pragma unroll
        for (int r = 0; r < 8; r++) {
          float av = a.hbuf[(size_t)(row0 + r) * H + kk];
          accP[r] += av * b1; accQ[r] += av * b2;
        }
      }
#pragma unroll
      for (int r = 0; r < 8; r++) {
        a.P[(size_t)(row0 + r) * H + t] = accP[r];
        a.Q[(size_t)(row0 + r) * H + t] = accQ[r];
      }
    }
    gbar(a.bar);
    // ---- PB: h1 = relu(cnt*(P+bm) + A@Q + S@WmB); tsb = dinv2*(h1@Wd0) ----
    {
      float* rb = sf + half * H;
      for (int row = bid * 2 + half; row < NN; row += 512) {  // 8 iters, uniform
        __syncthreads();
        float acc = 0.f;
        int beg = a.rp[row], end = a.rp[row + 1];
        for (int e = beg; e < end; e++) acc += a.Q[(size_t)a.cols[e] * H + t];
        float v = (float)a.cnt[row] * (a.P[(size_t)row * H + t] + a.bm[t]) + acc;
#pragma unroll
        for (int m = 0; m < MEDGE; m++) v += a.S[row * 4 + m] * a.Wm[(280 + m) * H + t];
        v = fmaxf(v, 0.f);
        a.h1[(size_t)row * H + t] = v;
        rb[t] = v;
        __syncthreads();
        float o = 0.f;
#pragma unroll 4
        for (int kk = 0; kk < H; kk++) o += rb[kk] * a.Wd0[kk * H + t];
        a.tsb[(size_t)row * H + t] = o * a.dinv2[row];
      }
    }
    gbar(a.bar);
    // ---- PC: GCN0 spmm epilogue + level-0 score/keys ----
    {
      for (int row = bid * 2 + half; row < NN; row += 512) {
        __syncthreads();
        float acc = 0.f;
        int beg = a.rp[row], end = a.rp[row + 1];
        for (int e = beg; e < end; e++) acc += a.tsb[(size_t)a.cols[e] * H + t];
        float v = a.dinv2[row] * (acc + 2.f * a.tsb[(size_t)row * H + t]) + a.bd0[t];
        v = fmaxf(v, 0.f);
        a.x0[(size_t)row * H + t] = v;
        float s = v * a.pool_w[t];
#pragma unroll
        for (int off = 32; off > 0; off >>= 1) s += __shfl_down(s, off);
        if (lane == 0) sf[half * 2 + wv] = s;
        __syncthreads();
        if (t == 0) {
          float sc = sf[half * 2] + sf[half * 2 + 1];
          sc = tanhf(sc / a.pwn[0]);
          a.score[row] = sc;
          unsigned u = __float_as_uint(sc + 0.0f);
          u ^= ((unsigned)((int)u >> 31)) | 0x80000000u;
          a.keys[row] = ((unsigned long long)u << 12) | (unsigned)(4095 - row);
        }
      }
    }
    gbar(a.bar);

    // ---- down path ----
#pragma unroll
    for (int i = 0; i < 5; i++) {
      toprank_ph(smem, a.keys, a.score, SZ[i], KL[i],
                 a.permb + i * 832, a.svb + i * 832, a.rankb + i * NN);
      gbar(a.bar);
      if (i == 0) a820_ph(smem, a.rp, a.cols, a.permb, a.A820, a.dv820);
      else augpool_ph(smem, Aarr[i - 1], SZ[i], a.permb + i * 832, KL[i], Aarr[i], dvarr[i]);
      gbar(a.bar);
      mmW_ph(xs[i], a.Wd + i * H * H, KL[i], dvarr[i], a.svb + i * 832,
             a.permb + i * 832, a.tsb);
      gbar(a.bar);
      float* outx = (i < 4) ? xs[i + 1] : a.xcur;
      dgcn_ph(smem, Aarr[i], KL[i], a.tsb, dvarr[i], a.bd + i * H, 1, outx,
              (i < 4) ? i + 1 : -1, a.pool_w + ((i < 4) ? (i + 1) * H : 0),
              a.pwn, a.score, a.keys);
      gbar(a.bar);
    }

    // ---- up path ----
#pragma unroll
    for (int i = 0; i < 5; i++) {
      int j = 4 - i;
      if (j > 0) {
        upmm_ph(xs[j], a.rankb + j * NN, KL[j], a.xcur, a.Wu + i * H * H,
                dvarr[j - 1], a.tsb, SZ[j]);
        gbar(a.bar);
        dgcn_ph(smem, Aarr[j - 1], SZ[j], a.tsb, dvarr[j - 1], a.bu + i * H,
                (i < 4) ? 1 : 0, a.xcur, -1, a.pool_w, a.pwn, a.score, a.keys);
        gbar(a.bar);
      } else {
        upmm_ph(a.x0, a.rankb, KL[0], a.xcur, a.Wu + 4 * H * H, a.dinv2, a.tsb, NN);
        gbar(a.bar);
        // spmm_out: h2 -> hbuf (next-step h), fused outproj -> ts2
        for (int row = bid * 2 + half; row < NN; row += 512) {
          __syncthreads();
          float acc = 0.f;
          int beg = a.rp[row], end = a.rp[row + 1];
          for (int e = beg; e < end; e++) acc += a.tsb[(size_t)a.cols[e] * H + t];
          float h2 = a.dinv2[row] * (acc + 2.f * a.tsb[(size_t)row * H + t]) + a.bu[4 * H + t];
          a.hbuf[(size_t)row * H + t] = h2;
          float h1v = a.h1[(size_t)row * H + t];
          float h2r = fmaxf(h2, 0.f);
          float p0 = h1v * a.Wout[t * 4 + 0] + h2r * a.Wout[(H + t) * 4 + 0];
          float p1 = h1v * a.Wout[t * 4 + 1] + h2r * a.Wout[(H + t) * 4 + 1];
          float p2 = h1v * a.Wout[t * 4 + 2] + h2r * a.Wout[(H + t) * 4 + 2];
          float p3 = h1v * a.Wout[t * 4 + 3] + h2r * a.Wout[(H + t) * 4 + 3];
#pragma unroll
          for (int off = 32; off > 0; off >>= 1) {
            p0 += __shfl_down(p0, off); p1 += __shfl_down(p1, off);
            p2 += __shfl_down(p2, off); p3 += __shfl_down(p3, off);
          }
          if (lane == 0) {
            float* w = sf + (half * 2 + wv) * 4;
            w[0] = p0; w[1] = p1; w[2] = p2; w[3] = p3;
          }
          __syncthreads();
          if (t == 0) {
            float d = a.dinv1[row];
#pragma unroll
            for (int c = 0; c < 4; c++)
              a.ts2[row * 4 + c] = d * (sf[(half * 2) * 4 + c] + sf[(half * 2 + 1) * 4 + c]);
          }
        }
        gbar(a.bar);
      }
    }

    // ---- final output GCN (fill=1) ----
    {
      int rw = tid >> 6;
      for (int row = bid * 4 + rw; row < NN; row += 1024) {  // 4 iters
        int f = lane & 3;
        float acc = 0.f;
        int beg = a.rp[row], end = a.rp[row + 1];
        for (int e = beg + (lane >> 2); e < end; e += 16) acc += a.ts2[a.cols[e] * 4 + f];
#pragma unroll
        for (int off = 32; off >= 4; off >>= 1) acc += __shfl_down(acc, off);
        if (lane < 4) {
          float v = a.dinv1[row] * (acc + a.ts2[row * 4 + f]) + a.bout[f];
          a.Fcur[row * 4 + f] = v;
          a.out[row * (NT * NF) + step * NF + f] = v;
        }
      }
    }
    gbar(a.bar);
  }
}

extern "C" void kernel_launch(void* const* d_in, const int* in_sizes, int n_in,
                              void* d_out, int out_size, void* d_ws, size_t ws_size,
                              hipStream_t stream) {
  KArgs a;
  a.F0        = (const float*)d_in[0];
  a.mesh_node = (const float*)d_in[1];
  a.mesh_edge = (const float*)d_in[2];
  a.Wm        = (const float*)d_in[3];
  a.bm        = (const float*)d_in[4];
  a.Wd0       = (const float*)d_in[5];
  a.bd0       = (const float*)d_in[6];
  a.Wd        = (const float*)d_in[7];
  a.bd        = (const float*)d_in[8];
  a.pool_w    = (const float*)d_in[9];
  a.Wu        = (const float*)d_in[10];
  a.bu        = (const float*)d_in[11];
  a.Wout      = (const float*)d_in[12];
  a.bout      = (const float*)d_in[13];
  a.ei        = (const int*)d_in[14];
  a.out       = (float*)d_out;

  char* p = (char*)d_ws;
  auto carve = [&](size_t bytes) -> char* {
    char* r = p;
    p += (bytes + 255) & ~(size_t)255;
    return r;
  };
  // zero-initialized span: bar, cnt, S, hbuf (single memset)
  a.bar    = (int*)carve(256);
  a.cnt    = (int*)carve((size_t)NN * 4);
  a.S      = (float*)carve((size_t)NN * MEDGE * 4);
  a.hbuf   = (float*)carve((size_t)NN * H * 4);
  size_t zspan = (size_t)(p - (char*)d_ws);

  a.rp     = (int*)carve((size_t)(NN + 1) * 4);
  a.cursor = (int*)carve((size_t)NN * 4);
  a.cols   = (int*)carve((size_t)EE * 4);
  a.permb  = (int*)carve((size_t)5 * 832 * 4);
  a.svb    = (float*)carve((size_t)5 * 832 * 4);
  a.rankb  = (int*)carve((size_t)5 * NN * 4);
  a.keys   = (unsigned long long*)carve((size_t)NN * 8);
  a.score  = (float*)carve((size_t)NN * 4);
  a.dinv2  = (float*)carve((size_t)NN * 4);
  a.dinv1  = (float*)carve((size_t)NN * 4);
  a.pwn    = (float*)carve(8 * 4);
  a.P      = (float*)carve((size_t)NN * H * 4);
  a.Q      = (float*)carve((size_t)NN * H * 4);
  a.h1     = (float*)carve((size_t)NN * H * 4);
  a.tsb    = (float*)carve((size_t)NN * H * 4);
  a.x0     = (float*)carve((size_t)NN * H * 4);
  a.x1     = (float*)carve((size_t)820 * H * 4);
  a.x2     = (float*)carve((size_t)164 * H * 4);
  a.x3     = (float*)carve((size_t)33 * H * 4);
  a.x4     = (float*)carve((size_t)7 * H * 4);
  a.xcur   = (float*)carve((size_t)820 * H * 4);
  a.A820   = (float*)carve((size_t)820 * 820 * 4);
  a.A164   = (float*)carve((size_t)164 * 164 * 4);
  a.A33    = (float*)carve((size_t)33 * 33 * 4);
  a.A7     = (float*)carve((size_t)7 * 7 * 4);
  a.A2b    = (float*)carve((size_t)2 * 2 * 4);
  a.dv820  = (float*)carve(820 * 4);
  a.dv164  = (float*)carve(164 * 4);
  a.dv33   = (float*)carve(33 * 4);
  a.dv7    = (float*)carve(7 * 4);
  a.dv2    = (float*)carve(2 * 4);
  a.ts2    = (float*)carve((size_t)NN * NF * 4);
  a.Fcur   = (float*)carve((size_t)NN * NF * 4);

  hipMemsetAsync(d_ws, 0, zspan, stream);
  mega<<<NBLK, 256, 0, stream>>>(a);
}

// Round 6
// 3498.140 us; speedup vs baseline: 3.1031x; 3.1031x over previous
//
#include <hip/hip_runtime.h>
#include <math.h>

#define NN 4096
#define EE 65536
#define H 128
#define NF 4
#define MNODE 8
#define MEDGE 4
#define NT 2

typedef unsigned long long ull;

// ---------------- setup ----------------
__global__ void k_setup_edges(const int* __restrict__ ei, const float* __restrict__ me,
                              int* __restrict__ cnt, float* __restrict__ S) {
  int e = blockIdx.x * 256 + threadIdx.x;  // EE = 256*256
  int d = ei[EE + e];
  atomicAdd(&cnt[d], 1);
#pragma unroll
  for (int m = 0; m < MEDGE; m++) atomicAdd(&S[d * 4 + m], me[e * 4 + m]);
}

__global__ void k_scan(const int* __restrict__ cnt, int* __restrict__ rp,
                       int* __restrict__ cursor) {
  __shared__ int sh[1024];
  int t = threadIdx.x;
  int v0 = cnt[4*t], v1 = cnt[4*t+1], v2 = cnt[4*t+2], v3 = cnt[4*t+3];
  int p1 = v0, p2 = v0 + v1, p3 = p2 + v2, tot = p3 + v3;
  sh[t] = tot; __syncthreads();
  for (int off = 1; off < 1024; off <<= 1) {
    int add = (t >= off) ? sh[t-off] : 0;
    __syncthreads();
    sh[t] += add;
    __syncthreads();
  }
  int base = sh[t] - tot;
  int r0 = base, r1 = base + p1, r2 = base + p2, r3 = base + p3;
  rp[4*t] = r0; rp[4*t+1] = r1; rp[4*t+2] = r2; rp[4*t+3] = r3;
  cursor[4*t] = r0; cursor[4*t+1] = r1; cursor[4*t+2] = r2; cursor[4*t+3] = r3;
  if (t == 1023) rp[NN] = sh[t];
}

// blocks 0..255: CSR fill; 256..271: dinv; 272: pool_w norms
__global__ void k_setup2(const int* __restrict__ ei, int* __restrict__ cursor,
                         int* __restrict__ cols, const int* __restrict__ cnt,
                         float* __restrict__ dinv2, float* __restrict__ dinv1,
                         const float* __restrict__ pw, float* __restrict__ pwn) {
  __shared__ float red[256];
  int bid = blockIdx.x, tid = threadIdx.x;
  if (bid < 256) {
    int e = bid * 256 + tid;
    int d = ei[EE + e], s0 = ei[e];
    int pos = atomicAdd(&cursor[d], 1);
    cols[pos] = s0;
  } else if (bid < 272) {
    int i = (bid - 256) * 256 + tid;
    float c = (float)cnt[i];
    dinv2[i] = 1.f / sqrtf(c + 2.f);
    dinv1[i] = 1.f / sqrtf(c + 1.f);
  } else {
    for (int l = 0; l < 5; l++) {
      float v = (tid < 128) ? pw[l * H + tid] : 0.f;
      red[tid] = v * v;
      __syncthreads();
      for (int off = 128; off > 0; off >>= 1) {
        if (tid < off) red[tid] += red[tid + off];
        __syncthreads();
      }
      if (tid == 0) pwn[l] = sqrtf(red[0]);
      __syncthreads();
    }
  }
}

// ---------------- edge-MLP projections ----------------
__global__ __launch_bounds__(128) void k_mmPQ(
    const float* __restrict__ F, const float* __restrict__ mn,
    const float* __restrict__ h, const float* __restrict__ Wm,
    float* __restrict__ P, float* __restrict__ Q) {
  constexpr int R = 8;
  int row0 = blockIdx.x * R;
  int t = threadIdx.x;
  float accP[R] = {}, accQ[R] = {};
#pragma unroll
  for (int kk = 0; kk < NF; kk++) {
    float b1 = Wm[kk*H + t], b2 = Wm[(140 + kk)*H + t];
#pragma unroll
    for (int r = 0; r < R; r++) {
      float a = F[(row0 + r)*NF + kk];
      accP[r] += a*b1; accQ[r] += a*b2;
    }
  }
#pragma unroll
  for (int kk = 0; kk < MNODE; kk++) {
    float b1 = Wm[(NF + kk)*H + t], b2 = Wm[(140 + NF + kk)*H + t];
#pragma unroll
    for (int r = 0; r < R; r++) {
      float a = mn[(row0 + r)*MNODE + kk];
      accP[r] += a*b1; accQ[r] += a*b2;
    }
  }
#pragma unroll 2
  for (int kk = 0; kk < H; kk++) {
    float b1 = Wm[(12 + kk)*H + t], b2 = Wm[(152 + kk)*H + t];
#pragma unroll
    for (int r = 0; r < R; r++) {
      float a = h[(size_t)(row0 + r)*H + kk];
      accP[r] += a*b1; accQ[r] += a*b2;
    }
  }
#pragma unroll
  for (int r = 0; r < R; r++) {
    P[(size_t)(row0 + r)*H + t] = accP[r];
    Q[(size_t)(row0 + r)*H + t] = accQ[r];
  }
}

// h1 = relu(cnt*(P+bm) + A@Q + S@WmB); tsb = h1@Wd0 (raw, dv applied downstream)
__global__ __launch_bounds__(128) void k_h1mm(
    const float* __restrict__ Q, const int* __restrict__ rp,
    const int* __restrict__ cols, const float* __restrict__ P,
    const float* __restrict__ bm, const float* __restrict__ S,
    const float* __restrict__ WmB, const int* __restrict__ cnt,
    const float* __restrict__ Wd0, float* __restrict__ h1, float* __restrict__ ts) {
  __shared__ float row[128];
  int i = blockIdx.x, t = threadIdx.x;
  float acc = 0.f;
  int beg = rp[i], end = rp[i+1];
  for (int e = beg; e < end; e++) acc += Q[(size_t)cols[e]*H + t];
  float v = (float)cnt[i] * (P[(size_t)i*H + t] + bm[t]) + acc;
#pragma unroll
  for (int m = 0; m < MEDGE; m++) v += S[i*4 + m] * WmB[m*H + t];
  v = fmaxf(v, 0.f);
  h1[(size_t)i*H + t] = v;
  row[t] = v;
  __syncthreads();
  float o = 0.f;
#pragma unroll 4
  for (int kk = 0; kk < H; kk++) o += row[kk] * Wd0[kk*H + t];
  ts[(size_t)i*H + t] = o;
}

// GCN0 (dv-mode) + level-0 score/keys
__global__ __launch_bounds__(128) void k_gcn0(
    const float* __restrict__ ts, const int* __restrict__ rp,
    const int* __restrict__ cols, const float* __restrict__ dv,
    const float* __restrict__ bias, const float* __restrict__ pw,
    const float* __restrict__ pwn, float* __restrict__ out,
    float* __restrict__ score, ull* __restrict__ keys) {
  __shared__ float sred[2];
  int i = blockIdx.x, t = threadIdx.x, wv = t >> 6, lane = t & 63;
  float acc = 0.f;
  int beg = rp[i], end = rp[i+1];
  for (int e = beg; e < end; e++) {
    int c = cols[e];
    acc += ts[(size_t)c*H + t] * dv[c];
  }
  float dvi = dv[i];
  float v = dvi * (acc + 2.f * dvi * ts[(size_t)i*H + t]) + bias[t];
  v = fmaxf(v, 0.f);
  out[(size_t)i*H + t] = v;
  float s = v * pw[t];
#pragma unroll
  for (int off = 32; off > 0; off >>= 1) s += __shfl_down(s, off);
  if (lane == 0) sred[wv] = s;
  __syncthreads();
  if (t == 0) {
    float sc = tanhf((sred[0] + sred[1]) / pwn[0]);
    score[i] = sc;
    unsigned u = __float_as_uint(sc + 0.0f);
    u ^= ((unsigned)((int)u >> 31)) | 0x80000000u;
    keys[i] = ((ull)u << 12) | (unsigned)(4095 - i);
  }
}

// exact jax.lax.top_k: rank = #{keys greater}; 16 i's/block, 16-way j split
__global__ __launch_bounds__(256) void k_toprank(
    const ull* __restrict__ keys, const float* __restrict__ score, int n, int k,
    int* __restrict__ perm, float* __restrict__ sv, int* __restrict__ rank) {
  __shared__ ull kls[4096];
  __shared__ int red[256];
  int bid = blockIdx.x, tid = threadIdx.x;
  for (int j = tid; j < n; j += 256) kls[j] = keys[j];
  __syncthreads();
  int ii = tid >> 4, jj = tid & 15;
  int i = bid * 16 + ii;
  ull ki = (i < n) ? kls[i] : ~0ULL;
  int r = 0;
  for (int j = jj; j < n; j += 16) r += (kls[j] > ki) ? 1 : 0;
  red[tid] = r;
  __syncthreads();
  for (int off = 8; off > 0; off >>= 1) {
    if (jj < off) red[tid] += red[tid + off];
    __syncthreads();
  }
  if (jj == 0 && i < n) {
    int rr = red[tid];
    rank[i] = rr;
    if (rr < k) { perm[rr] = i; sv[rr] = score[i]; }
  }
}

// blocks 0..819: A820 rows (CSR 2-hop) + dv; blocks 820..871: mmW(k=820)
__global__ __launch_bounds__(256) void k_a820mm(
    const int* __restrict__ rp, const int* __restrict__ cols,
    const int* __restrict__ perm, const float* __restrict__ sv,
    const float* __restrict__ x0, const float* __restrict__ W,
    float* __restrict__ A820, float* __restrict__ dv, float* __restrict__ gout) {
  __shared__ float acc[NN];
  __shared__ float red[256];
  int bid = blockIdx.x, tid = threadIdx.x;
  if (bid < 820) {
    for (int i2 = tid; i2 < NN; i2 += 256) acc[i2] = 0.f;
    __syncthreads();
    int pi = perm[bid];
    int beg = rp[pi], end = rp[pi + 1];
    for (int e = beg + tid; e < end; e += 256) {
      int c = cols[e];
      if (c != pi) atomicAdd(&acc[c], 1.f);
    }
    if (tid == 0) atomicAdd(&acc[pi], 1.f);
    for (int e0 = beg; e0 < end; e0++) {
      int c = cols[e0];
      if (c == pi) continue;
      int b2 = rp[c], e2 = rp[c + 1];
      for (int e = b2 + tid; e < e2; e += 256) {
        int c2 = cols[e];
        if (c2 != c) atomicAdd(&acc[c2], 1.f);
      }
      if (tid == 0) atomicAdd(&acc[c], 1.f);
    }
    __syncthreads();
    float ps = 0.f;
    for (int cc = tid; cc < 820; cc += 256) {
      float v = (cc == bid) ? 0.f : acc[perm[cc]];
      A820[(size_t)bid * 820 + cc] = v;
      ps += v;
    }
    red[tid] = ps;
    __syncthreads();
    for (int off = 128; off > 0; off >>= 1) {
      if (tid < off) red[tid] += red[tid + off];
      __syncthreads();
    }
    if (tid == 0) dv[bid] = 1.f / sqrtf(red[0] + 2.f);
  } else {
    int half = tid >> 7, t = tid & 127;
    int rbase = (bid - 820) * 16 + half * 8;
    float am[8]; int prs[8]; float svv[8];
#pragma unroll
    for (int j = 0; j < 8; j++) {
      int row = rbase + j;
      prs[j] = (row < 820) ? perm[row] : 0;
      svv[j] = (row < 820) ? sv[row] : 0.f;
      am[j] = 0.f;
    }
#pragma unroll 2
    for (int kk = 0; kk < H; kk++) {
      float b = W[kk * H + t];
#pragma unroll
      for (int j = 0; j < 8; j++) am[j] += x0[(size_t)prs[j] * H + kk] * b;
    }
#pragma unroll
    for (int j = 0; j < 8; j++) {
      int row = rbase + j;
      if (row < 820) gout[(size_t)row * H + t] = am[j] * svv[j];
    }
  }
}

// blocks 0..163: augpool row (A820 -> A164, nnz-compacted) + dv; 164..174: mmW(k=164)
__global__ __launch_bounds__(256) void k_augpool_mm(
    const float* __restrict__ A820, const int* __restrict__ perm,
    const float* __restrict__ sv, const float* __restrict__ x1,
    const float* __restrict__ W, float* __restrict__ A164,
    float* __restrict__ dv, float* __restrict__ gout) {
  __shared__ float rowv[832];
  __shared__ int rowi[832];
  __shared__ int nnzp;
  __shared__ float red[256];
  int bid = blockIdx.x, tid = threadIdx.x;
  if (bid < 164) {
    if (tid == 0) nnzp = 0;
    __syncthreads();
    int pr = perm[bid];
    for (int i2 = tid; i2 < 820; i2 += 256) {
      float v = A820[(size_t)pr * 820 + i2];
      if (v != 0.f) { int pos = atomicAdd(&nnzp, 1); rowv[pos] = v; rowi[pos] = i2; }
    }
    __syncthreads();
    int nnz = nnzp;
    int pc = (tid < 164) ? perm[tid] : 0;
    float acc = 0.f;
    for (int e = 0; e < nnz; e++) acc += rowv[e] * A820[(size_t)rowi[e] * 820 + pc];
    float v = 0.f;
    if (tid < 164) {
      v = (tid == bid) ? 0.f : (acc + 2.f * A820[(size_t)pr * 820 + pc]);
      A164[bid * 164 + tid] = v;
    }
    red[tid] = v;
    __syncthreads();
    for (int off = 128; off > 0; off >>= 1) {
      if (tid < off) red[tid] += red[tid + off];
      __syncthreads();
    }
    if (tid == 0) dv[bid] = 1.f / sqrtf(red[0] + 2.f);
  } else {
    int half = tid >> 7, t = tid & 127;
    int rbase = (bid - 164) * 16 + half * 8;
    float am[8]; int prs[8]; float svv[8];
#pragma unroll
    for (int j = 0; j < 8; j++) {
      int row = rbase + j;
      prs[j] = (row < 164) ? perm[row] : 0;
      svv[j] = (row < 164) ? sv[row] : 0.f;
      am[j] = 0.f;
    }
#pragma unroll 2
    for (int kk = 0; kk < H; kk++) {
      float b = W[kk * H + t];
#pragma unroll
      for (int j = 0; j < 8; j++) am[j] += x1[(size_t)prs[j] * H + kk] * b;
    }
#pragma unroll
    for (int j = 0; j < 8; j++) {
      int row = rbase + j;
      if (row < 164) gout[(size_t)row * H + t] = am[j] * svv[j];
    }
  }
}

// dense GCN (dv-mode, relu): out = dv_i*(sum_k A[i,k] dv_k g_k + 2 dv_i g_i)+b
__global__ __launch_bounds__(256) void k_dgcn(
    const float* __restrict__ A, int n, const float* __restrict__ gm,
    const float* __restrict__ dvk, const float* __restrict__ bias,
    float* __restrict__ outx, int lvl, const float* __restrict__ pw,
    const float* __restrict__ pwn, float* __restrict__ score, ull* __restrict__ keys) {
  __shared__ float wred[32];
  int tid = threadIdx.x, half = tid >> 7, t = tid & 127;
  int wv = (tid >> 6) & 1, lane = tid & 63;
  int rbase = blockIdx.x * 16 + half * 8;
  int rws[8]; float acc[8];
#pragma unroll
  for (int j = 0; j < 8; j++) {
    int row = rbase + j;
    rws[j] = (row < n) ? row : (n - 1);
    acc[j] = 0.f;
  }
#pragma unroll 4
  for (int kk = 0; kk < n; kk++) {
    float b = gm[(size_t)kk * H + t] * dvk[kk];
#pragma unroll
    for (int j = 0; j < 8; j++) acc[j] += A[(size_t)rws[j] * n + kk] * b;
  }
  float vj[8];
#pragma unroll
  for (int j = 0; j < 8; j++) {
    float dvr = dvk[rws[j]];
    float v = dvr * (acc[j] + 2.f * dvr * gm[(size_t)rws[j] * H + t]) + bias[t];
    v = fmaxf(v, 0.f);
    vj[j] = v;
    if (rbase + j < n) outx[(size_t)(rbase + j) * H + t] = v;
  }
  if (lvl >= 0) {
#pragma unroll
    for (int j = 0; j < 8; j++) {
      float s = vj[j] * pw[t];
#pragma unroll
      for (int off = 32; off > 0; off >>= 1) s += __shfl_down(s, off);
      if (lane == 0) wred[(half * 2 + wv) * 8 + j] = s;
    }
    __syncthreads();
    if (t == 0) {
#pragma unroll
      for (int j = 0; j < 8; j++) {
        int row = rbase + j;
        if (row < n) {
          float s = wred[(half * 2) * 8 + j] + wred[(half * 2 + 1) * 8 + j];
          s = tanhf(s / pwn[lvl]);
          score[row] = s;
          unsigned u = __float_as_uint(s + 0.0f);
          u ^= ((unsigned)((int)u >> 31)) | 0x80000000u;
          keys[row] = ((ull)u << 12) | (unsigned)(4095 - row);
        }
      }
    }
  }
}

// up: g = (res + scatter(xc by rank)) @ W  (raw; dv in consumer)
__global__ __launch_bounds__(256) void k_upmm(
    const float* __restrict__ res, const int* __restrict__ rank, int k,
    const float* __restrict__ xc, const float* __restrict__ W,
    float* __restrict__ outg, int n) {
  int tid = threadIdx.x, half = tid >> 7, t = tid & 127;
  int rbase = blockIdx.x * 16 + half * 8;
  float acc[8] = {};
  int rr[8]; float scl[8]; const float* up[8];
#pragma unroll
  for (int j = 0; j < 8; j++) {
    int row = rbase + j;
    int rv = (row < n) ? row : (n - 1);
    rr[j] = rv;
    int rnk = rank[rv];
    int kept = rnk < k;
    up[j] = xc + (size_t)(kept ? rnk : 0) * H;
    scl[j] = kept ? 1.f : 0.f;
  }
#pragma unroll 2
  for (int kk = 0; kk < H; kk++) {
    float b = W[kk * H + t];
#pragma unroll
    for (int j = 0; j < 8; j++)
      acc[j] += (res[(size_t)rr[j] * H + kk] + scl[j] * up[j][kk]) * b;
  }
#pragma unroll
  for (int j = 0; j < 8; j++) {
    int row = rbase + j;
    if (row < n) outg[(size_t)row * H + t] = acc[j];
  }
}

// final up SpMM (dv-mode, no relu) -> hbuf; fused outproj -> ts2
__global__ __launch_bounds__(128) void k_spmm_out(
    const float* __restrict__ ts, const int* __restrict__ rp,
    const int* __restrict__ cols, const float* __restrict__ dv,
    const float* __restrict__ bias, const float* __restrict__ h1,
    const float* __restrict__ Wout, const float* __restrict__ dinv1,
    float* __restrict__ hbuf, float* __restrict__ ts2) {
  __shared__ float wred[2][4];
  int i = blockIdx.x, t = threadIdx.x, wv = t >> 6, lane = t & 63;
  float acc = 0.f;
  int beg = rp[i], end = rp[i+1];
  for (int e = beg; e < end; e++) {
    int c = cols[e];
    acc += ts[(size_t)c*H + t] * dv[c];
  }
  float dvi = dv[i];
  float h2 = dvi * (acc + 2.f * dvi * ts[(size_t)i*H + t]) + bias[t];
  hbuf[(size_t)i*H + t] = h2;
  float h1v = h1[(size_t)i*H + t];
  float h2r = fmaxf(h2, 0.f);
  float p0 = h1v*Wout[t*4+0] + h2r*Wout[(H+t)*4+0];
  float p1 = h1v*Wout[t*4+1] + h2r*Wout[(H+t)*4+1];
  float p2 = h1v*Wout[t*4+2] + h2r*Wout[(H+t)*4+2];
  float p3 = h1v*Wout[t*4+3] + h2r*Wout[(H+t)*4+3];
#pragma unroll
  for (int off = 32; off > 0; off >>= 1) {
    p0 += __shfl_down(p0, off); p1 += __shfl_down(p1, off);
    p2 += __shfl_down(p2, off); p3 += __shfl_down(p3, off);
  }
  if (lane == 0) { wred[wv][0] = p0; wred[wv][1] = p1; wred[wv][2] = p2; wred[wv][3] = p3; }
  __syncthreads();
  if (t == 0) {
    float d = dinv1[i];
#pragma unroll
    for (int c = 0; c < 4; c++) ts2[i*4 + c] = d * (wred[0][c] + wred[1][c]);
  }
}

__global__ __launch_bounds__(256) void k_gcn_out(
    const float* __restrict__ ts2, const int* __restrict__ rp,
    const int* __restrict__ cols, const float* __restrict__ dinv1,
    const float* __restrict__ bout, float* __restrict__ Fcur,
    float* __restrict__ dout, int tstep) {
  int tid = threadIdx.x, rw = tid >> 6, lane = tid & 63;
  int row = blockIdx.x * 4 + rw;
  int f = lane & 3;
  float acc = 0.f;
  int beg = rp[row], end = rp[row + 1];
  for (int e = beg + (lane >> 2); e < end; e += 16) acc += ts2[cols[e]*4 + f];
#pragma unroll
  for (int off = 32; off >= 4; off >>= 1) acc += __shfl_down(acc, off);
  if (lane < 4) {
    float v = dinv1[row] * (acc + ts2[row*4 + f]) + bout[f];
    Fcur[row*4 + f] = v;
    dout[row*(NT*NF) + tstep*NF + f] = v;
  }
}

// -------- single-block tail: down levels 2..4 + up j=4..2, __syncthreads only --------
__global__ __launch_bounds__(1024) void k_tail(
    ull* __restrict__ keys, float* __restrict__ score, int* __restrict__ permb,
    float* __restrict__ svb, int* __restrict__ rankb,
    const float* __restrict__ A164, float* __restrict__ A33, float* __restrict__ A7,
    float* __restrict__ A2b, const float* __restrict__ dv164, float* __restrict__ dv33,
    float* __restrict__ dv7, float* __restrict__ dv2,
    const float* __restrict__ x2, float* __restrict__ x3, float* __restrict__ x4,
    float* __restrict__ xcur, float* __restrict__ gbuf,
    const float* __restrict__ Wd, const float* __restrict__ bd,
    const float* __restrict__ Wu, const float* __restrict__ bu,
    const float* __restrict__ pool_w, const float* __restrict__ pwn) {
  const int tid = threadIdx.x;
  const int g = tid >> 7, t = tid & 127, lane = tid & 63, wv = (tid >> 6) & 1;
  __shared__ ull skeys[192];
  __shared__ float red[1024];
  __shared__ float sred[16];

  const int SZt[3] = {164, 33, 7};
  const int KLt[3] = {33, 7, 2};
  const float* Ain[3] = {A164, A33, A7};
  float* Aout[3] = {A33, A7, A2b};
  float* dvout[3] = {dv33, dv7, dv2};
  const float* xin[3] = {x2, x3, x4};
  float* xout[3] = {x3, x4, xcur};

  // ---- down i=2,3,4 ----
  for (int s2 = 0; s2 < 3; s2++) {
    int i = 2 + s2, n = SZt[s2], k = KLt[s2];
    int* perm = permb + i * 832;
    float* sv = svb + i * 832;
    int* rank = rankb + i * NN;
    // toprank (n<=164)
    for (int j = tid; j < n; j += 1024) skeys[j] = keys[j];
    __syncthreads();
    if (tid < n) {
      ull ki = skeys[tid]; int r = 0;
      for (int j = 0; j < n; j++) r += (skeys[j] > ki) ? 1 : 0;
      rank[tid] = r;
      if (r < k) { perm[r] = tid; sv[r] = score[tid]; }
    }
    __syncthreads();
    // augpool (dense) + dv
    const float* Ap = Ain[s2];
    float* Ao = Aout[s2];
    float* dvo = dvout[s2];
    int nsw = (k + 7) / 8;
    for (int sw = 0; sw < nsw; sw++) {
      int r = sw * 8 + g;
      int pr = (r < k) ? perm[r] : 0;
      int pc = (t < k) ? perm[t] : 0;
      float acc = 0.f;
      for (int kk = 0; kk < n; kk++) acc += Ap[pr * n + kk] * Ap[kk * n + pc];
      float v = 0.f;
      if (r < k && t < k) {
        v = (t == r) ? 0.f : (acc + 2.f * Ap[pr * n + pc]);
        Ao[r * k + t] = v;
      }
      red[tid] = v;
      __syncthreads();
      for (int off = 64; off > 0; off >>= 1) {
        if (t < off) red[g * 128 + t] += red[g * 128 + t + off];
        __syncthreads();
      }
      if (t == 0 && r < k) dvo[r] = 1.f / sqrtf(red[g * 128] + 2.f);
      __syncthreads();
    }
    // mmW (64 rows cover k<=33)
    {
      const float* W = Wd + i * H * H;
      float am[8]; int prs[8]; float svv[8];
      int rbase = g * 8;
#pragma unroll
      for (int j = 0; j < 8; j++) {
        int row = rbase + j;
        prs[j] = (row < k) ? perm[row] : 0;
        svv[j] = (row < k) ? sv[row] : 0.f;
        am[j] = 0.f;
      }
      for (int kk = 0; kk < H; kk++) {
        float b = W[kk * H + t];
#pragma unroll
        for (int j = 0; j < 8; j++) am[j] += xin[s2][prs[j] * H + kk] * b;
      }
#pragma unroll
      for (int j = 0; j < 8; j++) {
        int row = rbase + j;
        if (row < k) gbuf[row * H + t] = am[j] * svv[j];
      }
    }
    __syncthreads();
    // dgcn on Ao (k x k) -> xout, keys for lvl i+1
    {
      float accd[8]; int rws[8];
      int rbase = g * 8;
#pragma unroll
      for (int j = 0; j < 8; j++) {
        int row = rbase + j;
        rws[j] = (row < k) ? row : (k - 1);
        accd[j] = 0.f;
      }
      for (int kk = 0; kk < k; kk++) {
        float b = gbuf[kk * H + t] * dvo[kk];
#pragma unroll
        for (int j = 0; j < 8; j++) accd[j] += Ao[rws[j] * k + kk] * b;
      }
      float vj[8];
#pragma unroll
      for (int j = 0; j < 8; j++) {
        float dvr = dvo[rws[j]];
        float v = dvr * (accd[j] + 2.f * dvr * gbuf[rws[j] * H + t]) + bd[i * H + t];
        v = fmaxf(v, 0.f);
        vj[j] = v;
        int row = rbase + j;
        if (row < k) xout[s2][row * H + t] = v;
      }
      __syncthreads();
      if (i < 4) {
        const float* pwl = pool_w + (i + 1) * H;
        for (int j = 0; j < 8; j++) {
          float s = vj[j] * pwl[t];
#pragma unroll
          for (int off = 32; off > 0; off >>= 1) s += __shfl_down(s, off);
          if (lane == 0) sred[g * 2 + wv] = s;
          __syncthreads();
          if (t == 0) {
            int row = g * 8 + j;
            if (row < k) {
              float sc = tanhf((sred[g * 2] + sred[g * 2 + 1]) / pwn[i + 1]);
              score[row] = sc;
              unsigned u = __float_as_uint(sc + 0.0f);
              u ^= ((unsigned)((int)u >> 31)) | 0x80000000u;
              keys[row] = ((ull)u << 12) | (unsigned)(4095 - row);
            }
          }
          __syncthreads();
        }
      }
    }
    __syncthreads();
  }

  // ---- up: uu=0 (j=4,n=7,k=2), 1 (j=3,n=33,k=7), 2 (j=2,n=164,k=33) ----
  const int SZu[3] = {7, 33, 164};
  const int KLu[3] = {2, 7, 33};
  const float* Au[3] = {A7, A33, A164};
  const float* dvu[3] = {dv7, dv33, dv164};
  const float* resu[3] = {x4, x3, x2};
  for (int uu = 0; uu < 3; uu++) {
    int j4 = 4 - uu, n = SZu[uu], k2 = KLu[uu];
    const int* rank = rankb + j4 * NN;
    const float* W = Wu + uu * H * H;
    const float* bias = bu + uu * H;
    int nsw = (n + 63) / 64;
    for (int sw = 0; sw < nsw; sw++) {
      float acc[8]; int rr[8]; float scl[8]; const float* up[8];
      int rbase = sw * 64 + g * 8;
#pragma unroll
      for (int jj = 0; jj < 8; jj++) {
        int row = rbase + jj;
        int rv = (row < n) ? row : (n - 1);
        rr[jj] = rv;
        int rnk = rank[rv];
        int kept = rnk < k2;
        up[jj] = xcur + (size_t)(kept ? rnk : 0) * H;
        scl[jj] = kept ? 1.f : 0.f;
        acc[jj] = 0.f;
      }
      for (int kk = 0; kk < H; kk++) {
        float b = W[kk * H + t];
#pragma unroll
        for (int jj = 0; jj < 8; jj++)
          acc[jj] += (resu[uu][rr[jj] * H + kk] + scl[jj] * up[jj][kk]) * b;
      }
#pragma unroll
      for (int jj = 0; jj < 8; jj++) {
        int row = rbase + jj;
        if (row < n) gbuf[row * H + t] = acc[jj];
      }
    }
    __syncthreads();
    for (int sw = 0; sw < nsw; sw++) {
      float accd[8]; int rws[8];
      int rbase = sw * 64 + g * 8;
#pragma unroll
      for (int jj = 0; jj < 8; jj++) {
        int row = rbase + jj;
        rws[jj] = (row < n) ? row : (n - 1);
        accd[jj] = 0.f;
      }
      for (int kk = 0; kk < n; kk++) {
        float b = gbuf[kk * H + t] * dvu[uu][kk];
#pragma unroll
        for (int jj = 0; jj < 8; jj++) accd[jj] += Au[uu][rws[jj] * n + kk] * b;
      }
#pragma unroll
      for (int jj = 0; jj < 8; jj++) {
        int row = rbase + jj;
        if (row < n) {
          float dvr = dvu[uu][row];
          float v = dvr * (accd[jj] + 2.f * dvr * gbuf[row * H + t]) + bias[t];
          xcur[row * H + t] = fmaxf(v, 0.f);
        }
      }
    }
    __syncthreads();
  }
}

extern "C" void kernel_launch(void* const* d_in, const int* in_sizes, int n_in,
                              void* d_out, int out_size, void* d_ws, size_t ws_size,
                              hipStream_t stream) {
  const float* F0        = (const float*)d_in[0];
  const float* mesh_node = (const float*)d_in[1];
  const float* mesh_edge = (const float*)d_in[2];
  const float* Wm        = (const float*)d_in[3];
  const float* bm        = (const float*)d_in[4];
  const float* Wd0       = (const float*)d_in[5];
  const float* bd0       = (const float*)d_in[6];
  const float* Wd        = (const float*)d_in[7];
  const float* bd        = (const float*)d_in[8];
  const float* pool_w    = (const float*)d_in[9];
  const float* Wu        = (const float*)d_in[10];
  const float* bu        = (const float*)d_in[11];
  const float* Wout      = (const float*)d_in[12];
  const float* bout      = (const float*)d_in[13];
  const int*   ei        = (const int*)d_in[14];
  float* out = (float*)d_out;

  char* p = (char*)d_ws;
  auto carve = [&](size_t bytes) -> char* {
    char* r = p;
    p += (bytes + 255) & ~(size_t)255;
    return r;
  };
  // zero-initialized span: cnt, S, hbuf
  int*   cnt   = (int*)carve((size_t)NN * 4);
  float* S     = (float*)carve((size_t)NN * MEDGE * 4);
  float* hbuf  = (float*)carve((size_t)NN * H * 4);
  size_t zspan = (size_t)(p - (char*)d_ws);

  int*   rp     = (int*)carve((size_t)(NN + 1) * 4);
  int*   cursor = (int*)carve((size_t)NN * 4);
  int*   cols   = (int*)carve((size_t)EE * 4);
  int*   permb  = (int*)carve((size_t)5 * 832 * 4);
  float* svb    = (float*)carve((size_t)5 * 832 * 4);
  int*   rankb  = (int*)carve((size_t)5 * NN * 4);
  ull*   keys   = (ull*)carve((size_t)NN * 8);
  float* score  = (float*)carve((size_t)NN * 4);
  float* dinv2  = (float*)carve((size_t)NN * 4);
  float* dinv1  = (float*)carve((size_t)NN * 4);
  float* pwn    = (float*)carve(8 * 4);
  float* P      = (float*)carve((size_t)NN * H * 4);
  float* Q      = (float*)carve((size_t)NN * H * 4);
  float* h1     = (float*)carve((size_t)NN * H * 4);
  float* tsb    = (float*)carve((size_t)NN * H * 4);
  float* x0     = (float*)carve((size_t)NN * H * 4);
  float* x1     = (float*)carve((size_t)820 * H * 4);
  float* x2     = (float*)carve((size_t)164 * H * 4);
  float* x3     = (float*)carve((size_t)33 * H * 4);
  float* x4     = (float*)carve((size_t)7 * H * 4);
  float* xcur   = (float*)carve((size_t)820 * H * 4);
  float* A820   = (float*)carve((size_t)820 * 820 * 4);
  float* A164   = (float*)carve((size_t)164 * 164 * 4);
  float* A33    = (float*)carve((size_t)33 * 33 * 4);
  float* A7     = (float*)carve((size_t)7 * 7 * 4);
  float* A2b    = (float*)carve((size_t)2 * 2 * 4);
  float* dv820  = (float*)carve(820 * 4);
  float* dv164  = (float*)carve(164 * 4);
  float* dv33   = (float*)carve(33 * 4);
  float* dv7    = (float*)carve(7 * 4);
  float* dv2    = (float*)carve(2 * 4);
  float* ts2    = (float*)carve((size_t)NN * NF * 4);
  float* Fcur   = (float*)carve((size_t)NN * NF * 4);

  // ---- setup: 4 nodes ----
  hipMemsetAsync(d_ws, 0, zspan, stream);
  k_setup_edges<<<256, 256, 0, stream>>>(ei, mesh_edge, cnt, S);
  k_scan<<<1, 1024, 0, stream>>>(cnt, rp, cursor);
  k_setup2<<<273, 256, 0, stream>>>(ei, cursor, cols, cnt, dinv2, dinv1, pool_w, pwn);

  for (int step = 0; step < NT; step++) {
    const float* Fsrc = step ? Fcur : F0;
    k_mmPQ<<<NN / 8, 128, 0, stream>>>(Fsrc, mesh_node, hbuf, Wm, P, Q);
    k_h1mm<<<NN, 128, 0, stream>>>(Q, rp, cols, P, bm, S, Wm + 280 * H, cnt, Wd0, h1, tsb);
    k_gcn0<<<NN, 128, 0, stream>>>(tsb, rp, cols, dinv2, bd0, pool_w, pwn, x0, score, keys);

    // level 0 (4096 -> 820)
    k_toprank<<<256, 256, 0, stream>>>(keys, score, NN, 820, permb, svb, rankb);
    k_a820mm<<<872, 256, 0, stream>>>(rp, cols, permb, svb, x0, Wd, A820, dv820, tsb);
    k_dgcn<<<52, 256, 0, stream>>>(A820, 820, tsb, dv820, bd, x1,
                                   1, pool_w + H, pwn, score, keys);
    // level 1 (820 -> 164)
    k_toprank<<<52, 256, 0, stream>>>(keys, score, 820, 164,
                                      permb + 832, svb + 832, rankb + NN);
    k_augpool_mm<<<175, 256, 0, stream>>>(A820, permb + 832, svb + 832, x1,
                                          Wd + H * H, A164, dv164, tsb);
    k_dgcn<<<11, 256, 0, stream>>>(A164, 164, tsb, dv164, bd + H, x2,
                                   2, pool_w + 2 * H, pwn, score, keys);
    // levels 2..4 down + up j=4..2 (single block)
    k_tail<<<1, 1024, 0, stream>>>(keys, score, permb, svb, rankb,
                                   A164, A33, A7, A2b, dv164, dv33, dv7, dv2,
                                   x2, x3, x4, xcur, tsb,
                                   Wd, bd, Wu, bu, pool_w, pwn);
    // up j=1 (n=820)
    k_upmm<<<52, 256, 0, stream>>>(x1, rankb + NN, 164, xcur, Wu + 3 * H * H, tsb, 820);
    k_dgcn<<<52, 256, 0, stream>>>(A820, 820, tsb, dv820, bu + 3 * H, xcur,
                                   -1, pool_w, pwn, score, keys);
    // up j=0 (n=4096) + output
    k_upmm<<<256, 256, 0, stream>>>(x0, rankb, 820, xcur, Wu + 4 * H * H, tsb, NN);
    k_spmm_out<<<NN, 128, 0, stream>>>(tsb, rp, cols, dinv2, bu + 4 * H, h1,
                                       Wout, dinv1, hbuf, ts2);
    k_gcn_out<<<1024, 256, 0, stream>>>(ts2, rp, cols, dinv1, bout, Fcur, out, step);
  }
}

// Round 7
// 1965.059 us; speedup vs baseline: 5.5241x; 1.7802x over previous
//
#include <hip/hip_runtime.h>
#include <math.h>

#define NN 4096
#define EE 65536
#define H 128
#define NF 4
#define MNODE 8
#define MEDGE 4
#define NT 2

typedef unsigned long long ull;

// ---------------- setup ----------------
__global__ void k_setup_edges(const int* __restrict__ ei, const float* __restrict__ me,
                              int* __restrict__ cnt, float* __restrict__ S) {
  int e = blockIdx.x * 256 + threadIdx.x;  // EE = 256*256
  int d = ei[EE + e];
  atomicAdd(&cnt[d], 1);
#pragma unroll
  for (int m = 0; m < MEDGE; m++) atomicAdd(&S[d * 4 + m], me[e * 4 + m]);
}

__global__ void k_scan(const int* __restrict__ cnt, int* __restrict__ rp,
                       int* __restrict__ cursor) {
  __shared__ int sh[1024];
  int t = threadIdx.x;
  int v0 = cnt[4*t], v1 = cnt[4*t+1], v2 = cnt[4*t+2], v3 = cnt[4*t+3];
  int p1 = v0, p2 = v0 + v1, p3 = p2 + v2, tot = p3 + v3;
  sh[t] = tot; __syncthreads();
  for (int off = 1; off < 1024; off <<= 1) {
    int add = (t >= off) ? sh[t-off] : 0;
    __syncthreads();
    sh[t] += add;
    __syncthreads();
  }
  int base = sh[t] - tot;
  int r0 = base, r1 = base + p1, r2 = base + p2, r3 = base + p3;
  rp[4*t] = r0; rp[4*t+1] = r1; rp[4*t+2] = r2; rp[4*t+3] = r3;
  cursor[4*t] = r0; cursor[4*t+1] = r1; cursor[4*t+2] = r2; cursor[4*t+3] = r3;
  if (t == 1023) rp[NN] = sh[t];
}

// blocks 0..255: CSR fill; 256..271: dinv; 272: pool_w norms
__global__ void k_setup2(const int* __restrict__ ei, int* __restrict__ cursor,
                         int* __restrict__ cols, const int* __restrict__ cnt,
                         float* __restrict__ dinv2, float* __restrict__ dinv1,
                         const float* __restrict__ pw, float* __restrict__ pwn) {
  __shared__ float red[256];
  int bid = blockIdx.x, tid = threadIdx.x;
  if (bid < 256) {
    int e = bid * 256 + tid;
    int d = ei[EE + e], s0 = ei[e];
    int pos = atomicAdd(&cursor[d], 1);
    cols[pos] = s0;
  } else if (bid < 272) {
    int i = (bid - 256) * 256 + tid;
    float c = (float)cnt[i];
    dinv2[i] = 1.f / sqrtf(c + 2.f);
    dinv1[i] = 1.f / sqrtf(c + 1.f);
  } else {
    for (int l = 0; l < 5; l++) {
      float v = (tid < 128) ? pw[l * H + tid] : 0.f;
      red[tid] = v * v;
      __syncthreads();
      for (int off = 128; off > 0; off >>= 1) {
        if (tid < off) red[tid] += red[tid + off];
        __syncthreads();
      }
      if (tid == 0) pwn[l] = sqrtf(red[0]);
      __syncthreads();
    }
  }
}

// ---------------- edge-MLP projections ----------------
__global__ __launch_bounds__(128) void k_mmPQ(
    const float* __restrict__ F, const float* __restrict__ mn,
    const float* __restrict__ h, const float* __restrict__ Wm,
    float* __restrict__ P, float* __restrict__ Q) {
  constexpr int R = 8;
  int row0 = blockIdx.x * R;
  int t = threadIdx.x;
  float accP[R] = {}, accQ[R] = {};
#pragma unroll
  for (int kk = 0; kk < NF; kk++) {
    float b1 = Wm[kk*H + t], b2 = Wm[(140 + kk)*H + t];
#pragma unroll
    for (int r = 0; r < R; r++) {
      float a = F[(row0 + r)*NF + kk];
      accP[r] += a*b1; accQ[r] += a*b2;
    }
  }
#pragma unroll
  for (int kk = 0; kk < MNODE; kk++) {
    float b1 = Wm[(NF + kk)*H + t], b2 = Wm[(140 + NF + kk)*H + t];
#pragma unroll
    for (int r = 0; r < R; r++) {
      float a = mn[(row0 + r)*MNODE + kk];
      accP[r] += a*b1; accQ[r] += a*b2;
    }
  }
#pragma unroll 2
  for (int kk = 0; kk < H; kk++) {
    float b1 = Wm[(12 + kk)*H + t], b2 = Wm[(152 + kk)*H + t];
#pragma unroll
    for (int r = 0; r < R; r++) {
      float a = h[(size_t)(row0 + r)*H + kk];
      accP[r] += a*b1; accQ[r] += a*b2;
    }
  }
#pragma unroll
  for (int r = 0; r < R; r++) {
    P[(size_t)(row0 + r)*H + t] = accP[r];
    Q[(size_t)(row0 + r)*H + t] = accQ[r];
  }
}

// h1 = relu(cnt*(P+bm) + A@Q + S@WmB); tsb = h1@Wd0 (raw, dv applied downstream)
__global__ __launch_bounds__(128) void k_h1mm(
    const float* __restrict__ Q, const int* __restrict__ rp,
    const int* __restrict__ cols, const float* __restrict__ P,
    const float* __restrict__ bm, const float* __restrict__ S,
    const float* __restrict__ WmB, const int* __restrict__ cnt,
    const float* __restrict__ Wd0, float* __restrict__ h1, float* __restrict__ ts) {
  __shared__ float row[128];
  int i = blockIdx.x, t = threadIdx.x;
  float acc = 0.f;
  int beg = rp[i], end = rp[i+1];
  for (int e = beg; e < end; e++) acc += Q[(size_t)cols[e]*H + t];
  float v = (float)cnt[i] * (P[(size_t)i*H + t] + bm[t]) + acc;
#pragma unroll
  for (int m = 0; m < MEDGE; m++) v += S[i*4 + m] * WmB[m*H + t];
  v = fmaxf(v, 0.f);
  h1[(size_t)i*H + t] = v;
  row[t] = v;
  __syncthreads();
  float o = 0.f;
#pragma unroll 4
  for (int kk = 0; kk < H; kk++) o += row[kk] * Wd0[kk*H + t];
  ts[(size_t)i*H + t] = o;
}

// GCN0 (dv-mode) + level-0 score/keys
__global__ __launch_bounds__(128) void k_gcn0(
    const float* __restrict__ ts, const int* __restrict__ rp,
    const int* __restrict__ cols, const float* __restrict__ dv,
    const float* __restrict__ bias, const float* __restrict__ pw,
    const float* __restrict__ pwn, float* __restrict__ out,
    float* __restrict__ score, ull* __restrict__ keys) {
  __shared__ float sred[2];
  int i = blockIdx.x, t = threadIdx.x, wv = t >> 6, lane = t & 63;
  float acc = 0.f;
  int beg = rp[i], end = rp[i+1];
  for (int e = beg; e < end; e++) {
    int c = cols[e];
    acc += ts[(size_t)c*H + t] * dv[c];
  }
  float dvi = dv[i];
  float v = dvi * (acc + 2.f * dvi * ts[(size_t)i*H + t]) + bias[t];
  v = fmaxf(v, 0.f);
  out[(size_t)i*H + t] = v;
  float s = v * pw[t];
#pragma unroll
  for (int off = 32; off > 0; off >>= 1) s += __shfl_down(s, off);
  if (lane == 0) sred[wv] = s;
  __syncthreads();
  if (t == 0) {
    float sc = tanhf((sred[0] + sred[1]) / pwn[0]);
    score[i] = sc;
    unsigned u = __float_as_uint(sc + 0.0f);
    u ^= ((unsigned)((int)u >> 31)) | 0x80000000u;
    keys[i] = ((ull)u << 12) | (unsigned)(4095 - i);
  }
}

// exact jax.lax.top_k: rank = #{keys greater}; 16 i's/block, 16-way j split
__global__ __launch_bounds__(256) void k_toprank(
    const ull* __restrict__ keys, const float* __restrict__ score, int n, int k,
    int* __restrict__ perm, float* __restrict__ sv, int* __restrict__ rank) {
  __shared__ ull kls[4096];
  __shared__ int red[256];
  int bid = blockIdx.x, tid = threadIdx.x;
  for (int j = tid; j < n; j += 256) kls[j] = keys[j];
  __syncthreads();
  int ii = tid >> 4, jj = tid & 15;
  int i = bid * 16 + ii;
  ull ki = (i < n) ? kls[i] : ~0ULL;
  int r = 0;
  for (int j = jj; j < n; j += 16) r += (kls[j] > ki) ? 1 : 0;
  red[tid] = r;
  __syncthreads();
  for (int off = 8; off > 0; off >>= 1) {
    if (jj < off) red[tid] += red[tid + off];
    __syncthreads();
  }
  if (jj == 0 && i < n) {
    int rr = red[tid];
    rank[i] = rr;
    if (rr < k) { perm[rr] = i; sv[rr] = score[i]; }
  }
}

// blocks 0..819: A820 rows (CSR 2-hop) + dv; blocks 820..871: mmW(k=820)
__global__ __launch_bounds__(256) void k_a820mm(
    const int* __restrict__ rp, const int* __restrict__ cols,
    const int* __restrict__ perm, const float* __restrict__ sv,
    const float* __restrict__ x0, const float* __restrict__ W,
    float* __restrict__ A820, float* __restrict__ dv, float* __restrict__ gout) {
  __shared__ float acc[NN];
  __shared__ float red[256];
  int bid = blockIdx.x, tid = threadIdx.x;
  if (bid < 820) {
    for (int i2 = tid; i2 < NN; i2 += 256) acc[i2] = 0.f;
    __syncthreads();
    int pi = perm[bid];
    int beg = rp[pi], end = rp[pi + 1];
    for (int e = beg + tid; e < end; e += 256) {
      int c = cols[e];
      if (c != pi) atomicAdd(&acc[c], 1.f);
    }
    if (tid == 0) atomicAdd(&acc[pi], 1.f);
    for (int e0 = beg; e0 < end; e0++) {
      int c = cols[e0];
      if (c == pi) continue;
      int b2 = rp[c], e2 = rp[c + 1];
      for (int e = b2 + tid; e < e2; e += 256) {
        int c2 = cols[e];
        if (c2 != c) atomicAdd(&acc[c2], 1.f);
      }
      if (tid == 0) atomicAdd(&acc[c], 1.f);
    }
    __syncthreads();
    float ps = 0.f;
    for (int cc = tid; cc < 820; cc += 256) {
      float v = (cc == bid) ? 0.f : acc[perm[cc]];
      A820[(size_t)bid * 820 + cc] = v;
      ps += v;
    }
    red[tid] = ps;
    __syncthreads();
    for (int off = 128; off > 0; off >>= 1) {
      if (tid < off) red[tid] += red[tid + off];
      __syncthreads();
    }
    if (tid == 0) dv[bid] = 1.f / sqrtf(red[0] + 2.f);
  } else {
    int half = tid >> 7, t = tid & 127;
    int rbase = (bid - 820) * 16 + half * 8;
    float am[8]; int prs[8]; float svv[8];
#pragma unroll
    for (int j = 0; j < 8; j++) {
      int row = rbase + j;
      prs[j] = (row < 820) ? perm[row] : 0;
      svv[j] = (row < 820) ? sv[row] : 0.f;
      am[j] = 0.f;
    }
#pragma unroll 2
    for (int kk = 0; kk < H; kk++) {
      float b = W[kk * H + t];
#pragma unroll
      for (int j = 0; j < 8; j++) am[j] += x0[(size_t)prs[j] * H + kk] * b;
    }
#pragma unroll
    for (int j = 0; j < 8; j++) {
      int row = rbase + j;
      if (row < 820) gout[(size_t)row * H + t] = am[j] * svv[j];
    }
  }
}

// blocks 0..163: augpool row (A820 -> A164, nnz-compacted) + dv; 164..174: mmW(k=164)
__global__ __launch_bounds__(256) void k_augpool_mm(
    const float* __restrict__ A820, const int* __restrict__ perm,
    const float* __restrict__ sv, const float* __restrict__ x1,
    const float* __restrict__ W, float* __restrict__ A164,
    float* __restrict__ dv, float* __restrict__ gout) {
  __shared__ float rowv[832];
  __shared__ int rowi[832];
  __shared__ int nnzp;
  __shared__ float red[256];
  int bid = blockIdx.x, tid = threadIdx.x;
  if (bid < 164) {
    if (tid == 0) nnzp = 0;
    __syncthreads();
    int pr = perm[bid];
    for (int i2 = tid; i2 < 820; i2 += 256) {
      float v = A820[(size_t)pr * 820 + i2];
      if (v != 0.f) { int pos = atomicAdd(&nnzp, 1); rowv[pos] = v; rowi[pos] = i2; }
    }
    __syncthreads();
    int nnz = nnzp;
    int pc = (tid < 164) ? perm[tid] : 0;
    float acc = 0.f;
    for (int e = 0; e < nnz; e++) acc += rowv[e] * A820[(size_t)rowi[e] * 820 + pc];
    float v = 0.f;
    if (tid < 164) {
      v = (tid == bid) ? 0.f : (acc + 2.f * A820[(size_t)pr * 820 + pc]);
      A164[bid * 164 + tid] = v;
    }
    red[tid] = v;
    __syncthreads();
    for (int off = 128; off > 0; off >>= 1) {
      if (tid < off) red[tid] += red[tid + off];
      __syncthreads();
    }
    if (tid == 0) dv[bid] = 1.f / sqrtf(red[0] + 2.f);
  } else {
    int half = tid >> 7, t = tid & 127;
    int rbase = (bid - 164) * 16 + half * 8;
    float am[8]; int prs[8]; float svv[8];
#pragma unroll
    for (int j = 0; j < 8; j++) {
      int row = rbase + j;
      prs[j] = (row < 164) ? perm[row] : 0;
      svv[j] = (row < 164) ? sv[row] : 0.f;
      am[j] = 0.f;
    }
#pragma unroll 2
    for (int kk = 0; kk < H; kk++) {
      float b = W[kk * H + t];
#pragma unroll
      for (int j = 0; j < 8; j++) am[j] += x1[(size_t)prs[j] * H + kk] * b;
    }
#pragma unroll
    for (int j = 0; j < 8; j++) {
      int row = rbase + j;
      if (row < 164) gout[(size_t)row * H + t] = am[j] * svv[j];
    }
  }
}

// dense GCN (dv-mode, relu): out = dv_i*(sum_k A[i,k] dv_k g_k + 2 dv_i g_i)+b
__global__ __launch_bounds__(256) void k_dgcn(
    const float* __restrict__ A, int n, const float* __restrict__ gm,
    const float* __restrict__ dvk, const float* __restrict__ bias,
    float* __restrict__ outx, int lvl, const float* __restrict__ pw,
    const float* __restrict__ pwn, float* __restrict__ score, ull* __restrict__ keys) {
  __shared__ float wred[32];
  int tid = threadIdx.x, half = tid >> 7, t = tid & 127;
  int wv = (tid >> 6) & 1, lane = tid & 63;
  int rbase = blockIdx.x * 16 + half * 8;
  int rws[8]; float acc[8];
#pragma unroll
  for (int j = 0; j < 8; j++) {
    int row = rbase + j;
    rws[j] = (row < n) ? row : (n - 1);
    acc[j] = 0.f;
  }
#pragma unroll 4
  for (int kk = 0; kk < n; kk++) {
    float b = gm[(size_t)kk * H + t] * dvk[kk];
#pragma unroll
    for (int j = 0; j < 8; j++) acc[j] += A[(size_t)rws[j] * n + kk] * b;
  }
  float vj[8];
#pragma unroll
  for (int j = 0; j < 8; j++) {
    float dvr = dvk[rws[j]];
    float v = dvr * (acc[j] + 2.f * dvr * gm[(size_t)rws[j] * H + t]) + bias[t];
    v = fmaxf(v, 0.f);
    vj[j] = v;
    if (rbase + j < n) outx[(size_t)(rbase + j) * H + t] = v;
  }
  if (lvl >= 0) {
#pragma unroll
    for (int j = 0; j < 8; j++) {
      float s = vj[j] * pw[t];
#pragma unroll
      for (int off = 32; off > 0; off >>= 1) s += __shfl_down(s, off);
      if (lane == 0) wred[(half * 2 + wv) * 8 + j] = s;
    }
    __syncthreads();
    if (t == 0) {
#pragma unroll
      for (int j = 0; j < 8; j++) {
        int row = rbase + j;
        if (row < n) {
          float s = wred[(half * 2) * 8 + j] + wred[(half * 2 + 1) * 8 + j];
          s = tanhf(s / pwn[lvl]);
          score[row] = s;
          unsigned u = __float_as_uint(s + 0.0f);
          u ^= ((unsigned)((int)u >> 31)) | 0x80000000u;
          keys[row] = ((ull)u << 12) | (unsigned)(4095 - row);
        }
      }
    }
  }
}

// up: g = (res + scatter(xc by rank)) @ W  (raw; dv in consumer)
__global__ __launch_bounds__(256) void k_upmm(
    const float* __restrict__ res, const int* __restrict__ rank, int k,
    const float* __restrict__ xc, const float* __restrict__ W,
    float* __restrict__ outg, int n) {
  int tid = threadIdx.x, half = tid >> 7, t = tid & 127;
  int rbase = blockIdx.x * 16 + half * 8;
  float acc[8] = {};
  int rr[8]; float scl[8]; const float* up[8];
#pragma unroll
  for (int j = 0; j < 8; j++) {
    int row = rbase + j;
    int rv = (row < n) ? row : (n - 1);
    rr[j] = rv;
    int rnk = rank[rv];
    int kept = rnk < k;
    up[j] = xc + (size_t)(kept ? rnk : 0) * H;
    scl[j] = kept ? 1.f : 0.f;
  }
#pragma unroll 2
  for (int kk = 0; kk < H; kk++) {
    float b = W[kk * H + t];
#pragma unroll
    for (int j = 0; j < 8; j++)
      acc[j] += (res[(size_t)rr[j] * H + kk] + scl[j] * up[j][kk]) * b;
  }
#pragma unroll
  for (int j = 0; j < 8; j++) {
    int row = rbase + j;
    if (row < n) outg[(size_t)row * H + t] = acc[j];
  }
}

// final up SpMM (dv-mode, no relu) -> hbuf; fused outproj -> ts2
__global__ __launch_bounds__(128) void k_spmm_out(
    const float* __restrict__ ts, const int* __restrict__ rp,
    const int* __restrict__ cols, const float* __restrict__ dv,
    const float* __restrict__ bias, const float* __restrict__ h1,
    const float* __restrict__ Wout, const float* __restrict__ dinv1,
    float* __restrict__ hbuf, float* __restrict__ ts2) {
  __shared__ float wred[2][4];
  int i = blockIdx.x, t = threadIdx.x, wv = t >> 6, lane = t & 63;
  float acc = 0.f;
  int beg = rp[i], end = rp[i+1];
  for (int e = beg; e < end; e++) {
    int c = cols[e];
    acc += ts[(size_t)c*H + t] * dv[c];
  }
  float dvi = dv[i];
  float h2 = dvi * (acc + 2.f * dvi * ts[(size_t)i*H + t]) + bias[t];
  hbuf[(size_t)i*H + t] = h2;
  float h1v = h1[(size_t)i*H + t];
  float h2r = fmaxf(h2, 0.f);
  float p0 = h1v*Wout[t*4+0] + h2r*Wout[(H+t)*4+0];
  float p1 = h1v*Wout[t*4+1] + h2r*Wout[(H+t)*4+1];
  float p2 = h1v*Wout[t*4+2] + h2r*Wout[(H+t)*4+2];
  float p3 = h1v*Wout[t*4+3] + h2r*Wout[(H+t)*4+3];
#pragma unroll
  for (int off = 32; off > 0; off >>= 1) {
    p0 += __shfl_down(p0, off); p1 += __shfl_down(p1, off);
    p2 += __shfl_down(p2, off); p3 += __shfl_down(p3, off);
  }
  if (lane == 0) { wred[wv][0] = p0; wred[wv][1] = p1; wred[wv][2] = p2; wred[wv][3] = p3; }
  __syncthreads();
  if (t == 0) {
    float d = dinv1[i];
#pragma unroll
    for (int c = 0; c < 4; c++) ts2[i*4 + c] = d * (wred[0][c] + wred[1][c]);
  }
}

__global__ __launch_bounds__(256) void k_gcn_out(
    const float* __restrict__ ts2, const int* __restrict__ rp,
    const int* __restrict__ cols, const float* __restrict__ dinv1,
    const float* __restrict__ bout, float* __restrict__ Fcur,
    float* __restrict__ dout, int tstep) {
  int tid = threadIdx.x, rw = tid >> 6, lane = tid & 63;
  int row = blockIdx.x * 4 + rw;
  int f = lane & 3;
  float acc = 0.f;
  int beg = rp[row], end = rp[row + 1];
  for (int e = beg + (lane >> 2); e < end; e += 16) acc += ts2[cols[e]*4 + f];
#pragma unroll
  for (int off = 32; off >= 4; off >>= 1) acc += __shfl_down(acc, off);
  if (lane < 4) {
    float v = dinv1[row] * (acc + ts2[row*4 + f]) + bout[f];
    Fcur[row*4 + f] = v;
    dout[row*(NT*NF) + tstep*NF + f] = v;
  }
}

// -------- single-block tail, hard-coded sizes, LDS-resident state --------
// levels: down 164->33->7->2, up 2->7->33->164. Only n=164 phases touch global.
__global__ __launch_bounds__(1024) void k_tail(
    const ull* __restrict__ gkeys, const float* __restrict__ gscore,
    const float* __restrict__ A164, const float* __restrict__ dv164,
    const float* __restrict__ x2, float* __restrict__ gb,  // tsb as g-scratch
    float* __restrict__ xcur,
    const float* __restrict__ Wd, const float* __restrict__ bd,
    const float* __restrict__ Wu, const float* __restrict__ bu,
    const float* __restrict__ pool_w, const float* __restrict__ pwn) {
  __shared__ float sm[16256];  // 63.5 KB
  const int tid = threadIdx.x;
  const int g = tid >> 7, t = tid & 127;
  float* x3    = sm + 0;      // 33*128 = 4224
  float* x4    = sm + 4224;   // 7*128  = 896
  float* xc    = sm + 5120;   // up-state, up to 33*128 = 4224
  float* A33   = sm + 9344;   // 1089
  float* A7s   = sm + 10433;  // 49
  float* A2s   = sm + 10482;  // 4
  float* dv33  = sm + 10486;  // 33
  float* dv7   = sm + 10519;  // 7
  float* dv2   = sm + 10526;  // 2
  float* dv164s= sm + 10528;  // 164
  int*  rank164= (int*)(sm + 10692);  // 164
  int*  rank33 = (int*)(sm + 10856);  // 33
  int*  rank7  = (int*)(sm + 10889);  // 7
  int*  perm2  = (int*)(sm + 10896);  // 33
  float* sv2   = sm + 10929;  // 33
  int*  perm3  = (int*)(sm + 10962);  // 7
  float* sv3   = sm + 10969;  // 7
  int*  perm4  = (int*)(sm + 10976);  // 2
  float* sv4   = sm + 10978;  // 2
  ull*  skey33 = (ull*)(sm + 10980);  // 33 ull (66 f), 8B-aligned
  float* ssc33 = sm + 11046;  // 33
  ull*  skey7  = (ull*)(sm + 11080);  // 7 ull (14 f)
  float* ssc7  = sm + 11094;  // 7
  float* scr   = sm + 11104;  // 5152 floats scratch

  // ---- D2 toprank: 164 -> 33 ----
  {
    ull* sk = (ull*)scr;
    for (int i = tid; i < 164; i += 1024) sk[i] = gkeys[i];
    for (int i = tid; i < 164; i += 1024) dv164s[i] = dv164[i];
    __syncthreads();
    if (tid < 164) {
      ull ki = sk[tid];
      int r = 0;
#pragma unroll 4
      for (int j = 0; j < 164; j++) r += (sk[j] > ki) ? 1 : 0;
      rank164[tid] = r;
      if (r < 33) { perm2[r] = tid; sv2[r] = gscore[tid]; }
    }
    __syncthreads();
  }
  // ---- D2 augment+pool: A164 -> A33 (+dv33). Col-batches staged in LDS ----
  for (int b = 0; b < 2; b++) {
    int c0 = b * 17, nc = (b == 0) ? 17 : 16;
    for (int o = tid; o < nc * 164; o += 1024) {
      int cb = o / 164, kk = o - cb * 164;
      scr[cb * 164 + kk] = A164[(size_t)kk * 164 + perm2[c0 + cb]];
    }
    __syncthreads();
    for (int o = tid; o < 33 * nc; o += 1024) {
      int r = o / nc, cb = o - r * nc;
      int c = c0 + cb;
      const float* Arow = A164 + (size_t)perm2[r] * 164;
      float acc = 0.f;
#pragma unroll 4
      for (int kk = 0; kk < 164; kk++) acc += Arow[kk] * scr[cb * 164 + kk];
      A33[r * 33 + c] = (r == c) ? 0.f : (acc + 2.f * Arow[perm2[c]]);
    }
    __syncthreads();
  }
  if (tid < 33) {
    float s = 0.f;
#pragma unroll
    for (int c = 0; c < 33; c++) s += A33[tid * 33 + c];
    dv33[tid] = 1.f / sqrtf(s + 2.f);
  }
  __syncthreads();
  // ---- D2 mmW: g = sv2 * (x2[perm2] @ Wd2); rows g+8j (+32 for g==0) ----
  {
    for (int o = tid; o < 33 * 128; o += 1024) {
      int r = o >> 7, cc = o & 127;
      scr[o] = x2[(size_t)perm2[r] * 128 + cc];
    }
    __syncthreads();
    const float* W = Wd + 2 * H * H;
    float acc[4] = {}; float acc32 = 0.f;
#pragma unroll 4
    for (int kk = 0; kk < 128; kk++) {
      float b = W[kk * 128 + t];
#pragma unroll
      for (int j = 0; j < 4; j++) acc[j] += scr[(g + 8 * j) * 128 + kk] * b;
      acc32 += scr[32 * 128 + kk] * b;
    }
    __syncthreads();
#pragma unroll
    for (int j = 0; j < 4; j++) {
      int r = g + 8 * j;
      scr[r * 128 + t] = acc[j] * sv2[r];
    }
    if (g == 0) scr[32 * 128 + t] = acc32 * sv2[32];
    __syncthreads();
  }
  // ---- D2 dgcn: x3 = relu(dv*(A33@(dv.g) + 2dv g) + bd2); keys lvl3 ----
  {
    float acc[4] = {}; float acc32 = 0.f;
#pragma unroll 2
    for (int kk = 0; kk < 33; kk++) {
      float b = scr[kk * 128 + t] * dv33[kk];
#pragma unroll
      for (int j = 0; j < 4; j++) acc[j] += A33[(g + 8 * j) * 33 + kk] * b;
      acc32 += A33[32 * 33 + kk] * b;
    }
    float bias = bd[2 * H + t];
#pragma unroll
    for (int j = 0; j < 4; j++) {
      int r = g + 8 * j;
      float dvr = dv33[r];
      x3[r * 128 + t] = fmaxf(dvr * (acc[j] + 2.f * dvr * scr[r * 128 + t]) + bias, 0.f);
    }
    if (g == 0) {
      float dvr = dv33[32];
      x3[32 * 128 + t] = fmaxf(dvr * (acc32 + 2.f * dvr * scr[32 * 128 + t]) + bias, 0.f);
    }
    __syncthreads();
    if (tid < 33) {
      const float* pw = pool_w + 3 * H;
      float s = 0.f;
#pragma unroll 4
      for (int c = 0; c < 128; c++) s += x3[tid * 128 + c] * pw[c];
      float sc = tanhf(s / pwn[3]);
      ssc33[tid] = sc;
      unsigned u = __float_as_uint(sc + 0.0f);
      u ^= ((unsigned)((int)u >> 31)) | 0x80000000u;
      skey33[tid] = ((ull)u << 12) | (unsigned)(4095 - tid);
    }
    __syncthreads();
  }
  // ---- D3: 33 -> 7 ----
  if (tid < 33) {
    ull ki = skey33[tid];
    int r = 0;
#pragma unroll
    for (int j = 0; j < 33; j++) r += (skey33[j] > ki) ? 1 : 0;
    rank33[tid] = r;
    if (r < 7) { perm3[r] = tid; sv3[r] = ssc33[tid]; }
  }
  __syncthreads();
  if (tid < 49) {
    int r = tid / 7, c = tid - r * 7;
    int pr = perm3[r], pc = perm3[c];
    float acc = 0.f;
#pragma unroll
    for (int kk = 0; kk < 33; kk++) acc += A33[pr * 33 + kk] * A33[kk * 33 + pc];
    A7s[tid] = (r == c) ? 0.f : (acc + 2.f * A33[pr * 33 + pc]);
  }
  __syncthreads();
  if (tid < 7) {
    float s = 0.f;
#pragma unroll
    for (int c = 0; c < 7; c++) s += A7s[tid * 7 + c];
    dv7[tid] = 1.f / sqrtf(s + 2.f);
  }
  __syncthreads();
  {
    const float* W = Wd + 3 * H * H;
    int pr = (g < 7) ? perm3[g] : 0;
    float acc = 0.f;
#pragma unroll 4
    for (int kk = 0; kk < 128; kk++) acc += x3[pr * 128 + kk] * W[kk * 128 + t];
    __syncthreads();
    if (g < 7) scr[g * 128 + t] = acc * sv3[g];
    __syncthreads();
    float acc2 = 0.f;
#pragma unroll
    for (int kk = 0; kk < 7; kk++)
      acc2 += ((g < 7) ? A7s[g * 7 + kk] : 0.f) * scr[kk * 128 + t] * dv7[kk];
    if (g < 7) {
      float dvr = dv7[g];
      x4[g * 128 + t] = fmaxf(dvr * (acc2 + 2.f * dvr * scr[g * 128 + t]) + bd[3 * H + t], 0.f);
    }
    __syncthreads();
    if (tid < 7) {
      const float* pw = pool_w + 4 * H;
      float s = 0.f;
#pragma unroll 4
      for (int c = 0; c < 128; c++) s += x4[tid * 128 + c] * pw[c];
      float sc = tanhf(s / pwn[4]);
      ssc7[tid] = sc;
      unsigned u = __float_as_uint(sc + 0.0f);
      u ^= ((unsigned)((int)u >> 31)) | 0x80000000u;
      skey7[tid] = ((ull)u << 12) | (unsigned)(4095 - tid);
    }
    __syncthreads();
  }
  // ---- D4: 7 -> 2 ----
  if (tid < 7) {
    ull ki = skey7[tid];
    int r = 0;
#pragma unroll
    for (int j = 0; j < 7; j++) r += (skey7[j] > ki) ? 1 : 0;
    rank7[tid] = r;
    if (r < 2) { perm4[r] = tid; sv4[r] = ssc7[tid]; }
  }
  __syncthreads();
  if (tid < 4) {
    int r = tid >> 1, c = tid & 1;
    int pr = perm4[r], pc = perm4[c];
    float acc = 0.f;
#pragma unroll
    for (int kk = 0; kk < 7; kk++) acc += A7s[pr * 7 + kk] * A7s[kk * 7 + pc];
    A2s[tid] = (r == c) ? 0.f : (acc + 2.f * A7s[pr * 7 + pc]);
  }
  __syncthreads();
  if (tid < 2) dv2[tid] = 1.f / sqrtf(A2s[tid * 2] + A2s[tid * 2 + 1] + 2.f);
  __syncthreads();
  {
    const float* W = Wd + 4 * H * H;
    int pr = (g < 2) ? perm4[g] : 0;
    float acc = 0.f;
#pragma unroll 4
    for (int kk = 0; kk < 128; kk++) acc += x4[pr * 128 + kk] * W[kk * 128 + t];
    __syncthreads();
    if (g < 2) scr[g * 128 + t] = acc * sv4[g];
    __syncthreads();
    if (g < 2) {
      float acc2 = A2s[g * 2 + (1 - g)] * scr[(1 - g) * 128 + t] * dv2[1 - g];
      float dvr = dv2[g];
      xc[g * 128 + t] = fmaxf(dvr * (acc2 + 2.f * dvr * scr[g * 128 + t]) + bd[4 * H + t], 0.f);
    }
    __syncthreads();
  }
  // ---- UP uu=0 (n=7, k=2) ----
  {
    const float* W = Wu;
    int rv = (g < 7) ? g : 0;
    int rnk = rank7[rv];
    int kept = rnk < 2;
    const float* up = xc + (kept ? rnk : 0) * 128;
    float scl = kept ? 1.f : 0.f;
    float acc = 0.f;
#pragma unroll 4
    for (int kk = 0; kk < 128; kk++)
      acc += (x4[rv * 128 + kk] + scl * up[kk]) * W[kk * 128 + t];
    __syncthreads();
    if (g < 7) scr[g * 128 + t] = acc;
    __syncthreads();
    float acc2 = 0.f;
#pragma unroll
    for (int kk = 0; kk < 7; kk++)
      acc2 += ((g < 7) ? A7s[g * 7 + kk] : 0.f) * scr[kk * 128 + t] * dv7[kk];
    if (g < 7) {
      float dvr = dv7[g];
      xc[g * 128 + t] = fmaxf(dvr * (acc2 + 2.f * dvr * scr[g * 128 + t]) + bu[t], 0.f);
    }
    __syncthreads();
  }
  // ---- UP uu=1 (n=33, k=7) ----
  {
    const float* W = Wu + H * H;
    float acc[4] = {}; float acc32 = 0.f;
    const float* ups[4]; float scl[4];
#pragma unroll
    for (int j = 0; j < 4; j++) {
      int r = g + 8 * j;
      int rnk = rank33[r];
      int kept = rnk < 7;
      ups[j] = xc + (kept ? rnk : 0) * 128;
      scl[j] = kept ? 1.f : 0.f;
    }
    int rnk32 = rank33[32];
    int kept32 = rnk32 < 7;
    const float* up32 = xc + (kept32 ? rnk32 : 0) * 128;
    float scl32 = kept32 ? 1.f : 0.f;
#pragma unroll 2
    for (int kk = 0; kk < 128; kk++) {
      float b = W[kk * 128 + t];
#pragma unroll
      for (int j = 0; j < 4; j++)
        acc[j] += (x3[(g + 8 * j) * 128 + kk] + scl[j] * ups[j][kk]) * b;
      acc32 += (x3[32 * 128 + kk] + scl32 * up32[kk]) * b;
    }
    __syncthreads();
#pragma unroll
    for (int j = 0; j < 4; j++) scr[(g + 8 * j) * 128 + t] = acc[j];
    if (g == 0) scr[32 * 128 + t] = acc32;
    __syncthreads();
    float acc2[4] = {}; float acc232 = 0.f;
#pragma unroll 2
    for (int kk = 0; kk < 33; kk++) {
      float b = scr[kk * 128 + t] * dv33[kk];
#pragma unroll
      for (int j = 0; j < 4; j++) acc2[j] += A33[(g + 8 * j) * 33 + kk] * b;
      acc232 += A33[32 * 33 + kk] * b;
    }
    float bias = bu[H + t];
    __syncthreads();
#pragma unroll
    for (int j = 0; j < 4; j++) {
      int r = g + 8 * j;
      float dvr = dv33[r];
      xc[r * 128 + t] = fmaxf(dvr * (acc2[j] + 2.f * dvr * scr[r * 128 + t]) + bias, 0.f);
    }
    if (g == 0) {
      float dvr = dv33[32];
      xc[32 * 128 + t] = fmaxf(dvr * (acc232 + 2.f * dvr * scr[32 * 128 + t]) + bias, 0.f);
    }
    __syncthreads();
  }
  // ---- UP uu=2 (n=164, k=33): g -> global gb; dgcn from global A164 -> xcur ----
  {
    const float* W = Wu + 2 * H * H;
    for (int s = 0; s < 3; s++) {
      float acc[7] = {};
      int rr[7]; float scl[7]; const float* ups[7];
#pragma unroll
      for (int j = 0; j < 7; j++) {
        int r = g + 8 * (7 * s + j);
        int rv = (r < 164) ? r : 163;
        rr[j] = rv;
        int rnk = rank164[rv];
        int kept = rnk < 33;
        ups[j] = xc + (kept ? rnk : 0) * 128;
        scl[j] = kept ? 1.f : 0.f;
      }
#pragma unroll 2
      for (int kk = 0; kk < 128; kk++) {
        float b = W[kk * 128 + t];
#pragma unroll
        for (int j = 0; j < 7; j++)
          acc[j] += (x2[(size_t)rr[j] * 128 + kk] + scl[j] * ups[j][kk]) * b;
      }
#pragma unroll
      for (int j = 0; j < 7; j++) {
        int r = g + 8 * (7 * s + j);
        if (r < 164) gb[(size_t)r * 128 + t] = acc[j];
      }
    }
    __syncthreads();
    float bias = bu[2 * H + t];
    for (int s = 0; s < 3; s++) {
      float acc[7] = {};
      int rr[7];
#pragma unroll
      for (int j = 0; j < 7; j++) {
        int r = g + 8 * (7 * s + j);
        rr[j] = (r < 164) ? r : 163;
      }
#pragma unroll 2
      for (int kk = 0; kk < 164; kk++) {
        float b = gb[(size_t)kk * 128 + t] * dv164s[kk];
#pragma unroll
        for (int j = 0; j < 7; j++) acc[j] += A164[(size_t)rr[j] * 164 + kk] * b;
      }
#pragma unroll
      for (int j = 0; j < 7; j++) {
        int r = g + 8 * (7 * s + j);
        if (r < 164) {
          float dvr = dv164s[r];
          float v = dvr * (acc[j] + 2.f * dvr * gb[(size_t)r * 128 + t]) + bias;
          xcur[(size_t)r * 128 + t] = fmaxf(v, 0.f);
        }
      }
    }
  }
}

extern "C" void kernel_launch(void* const* d_in, const int* in_sizes, int n_in,
                              void* d_out, int out_size, void* d_ws, size_t ws_size,
                              hipStream_t stream) {
  const float* F0        = (const float*)d_in[0];
  const float* mesh_node = (const float*)d_in[1];
  const float* mesh_edge = (const float*)d_in[2];
  const float* Wm        = (const float*)d_in[3];
  const float* bm        = (const float*)d_in[4];
  const float* Wd0       = (const float*)d_in[5];
  const float* bd0       = (const float*)d_in[6];
  const float* Wd        = (const float*)d_in[7];
  const float* bd        = (const float*)d_in[8];
  const float* pool_w    = (const float*)d_in[9];
  const float* Wu        = (const float*)d_in[10];
  const float* bu        = (const float*)d_in[11];
  const float* Wout      = (const float*)d_in[12];
  const float* bout      = (const float*)d_in[13];
  const int*   ei        = (const int*)d_in[14];
  float* out = (float*)d_out;

  char* p = (char*)d_ws;
  auto carve = [&](size_t bytes) -> char* {
    char* r = p;
    p += (bytes + 255) & ~(size_t)255;
    return r;
  };
  int*   cnt   = (int*)carve((size_t)NN * 4);
  float* S     = (float*)carve((size_t)NN * MEDGE * 4);
  float* hbuf  = (float*)carve((size_t)NN * H * 4);
  size_t zspan = (size_t)(p - (char*)d_ws);

  int*   rp     = (int*)carve((size_t)(NN + 1) * 4);
  int*   cursor = (int*)carve((size_t)NN * 4);
  int*   cols   = (int*)carve((size_t)EE * 4);
  int*   permb  = (int*)carve((size_t)5 * 832 * 4);
  float* svb    = (float*)carve((size_t)5 * 832 * 4);
  int*   rankb  = (int*)carve((size_t)5 * NN * 4);
  ull*   keys   = (ull*)carve((size_t)NN * 8);
  float* score  = (float*)carve((size_t)NN * 4);
  float* dinv2  = (float*)carve((size_t)NN * 4);
  float* dinv1  = (float*)carve((size_t)NN * 4);
  float* pwn    = (float*)carve(8 * 4);
  float* P      = (float*)carve((size_t)NN * H * 4);
  float* Q      = (float*)carve((size_t)NN * H * 4);
  float* h1     = (float*)carve((size_t)NN * H * 4);
  float* tsb    = (float*)carve((size_t)NN * H * 4);
  float* x0     = (float*)carve((size_t)NN * H * 4);
  float* x1     = (float*)carve((size_t)820 * H * 4);
  float* x2     = (float*)carve((size_t)164 * H * 4);
  float* xcur   = (float*)carve((size_t)820 * H * 4);
  float* A820   = (float*)carve((size_t)820 * 820 * 4);
  float* A164   = (float*)carve((size_t)164 * 164 * 4);
  float* dv820  = (float*)carve(820 * 4);
  float* dv164  = (float*)carve(164 * 4);
  float* ts2    = (float*)carve((size_t)NN * NF * 4);
  float* Fcur   = (float*)carve((size_t)NN * NF * 4);

  hipMemsetAsync(d_ws, 0, zspan, stream);
  k_setup_edges<<<256, 256, 0, stream>>>(ei, mesh_edge, cnt, S);
  k_scan<<<1, 1024, 0, stream>>>(cnt, rp, cursor);
  k_setup2<<<273, 256, 0, stream>>>(ei, cursor, cols, cnt, dinv2, dinv1, pool_w, pwn);

  for (int step = 0; step < NT; step++) {
    const float* Fsrc = step ? Fcur : F0;
    k_mmPQ<<<NN / 8, 128, 0, stream>>>(Fsrc, mesh_node, hbuf, Wm, P, Q);
    k_h1mm<<<NN, 128, 0, stream>>>(Q, rp, cols, P, bm, S, Wm + 280 * H, cnt, Wd0, h1, tsb);
    k_gcn0<<<NN, 128, 0, stream>>>(tsb, rp, cols, dinv2, bd0, pool_w, pwn, x0, score, keys);

    // level 0 (4096 -> 820)
    k_toprank<<<256, 256, 0, stream>>>(keys, score, NN, 820, permb, svb, rankb);
    k_a820mm<<<872, 256, 0, stream>>>(rp, cols, permb, svb, x0, Wd, A820, dv820, tsb);
    k_dgcn<<<52, 256, 0, stream>>>(A820, 820, tsb, dv820, bd, x1,
                                   1, pool_w + H, pwn, score, keys);
    // level 1 (820 -> 164)
    k_toprank<<<52, 256, 0, stream>>>(keys, score, 820, 164,
                                      permb + 832, svb + 832, rankb + NN);
    k_augpool_mm<<<175, 256, 0, stream>>>(A820, permb + 832, svb + 832, x1,
                                          Wd + H * H, A164, dv164, tsb);
    k_dgcn<<<11, 256, 0, stream>>>(A164, 164, tsb, dv164, bd + H, x2,
                                   2, pool_w + 2 * H, pwn, score, keys);
    // levels 2..4 down + up to n=164 (single block, LDS-resident)
    k_tail<<<1, 1024, 0, stream>>>(keys, score, A164, dv164, x2, tsb, xcur,
                                   Wd, bd, Wu, bu, pool_w, pwn);
    // up j=1 (n=820)
    k_upmm<<<52, 256, 0, stream>>>(x1, rankb + NN, 164, xcur, Wu + 3 * H * H, tsb, 820);
    k_dgcn<<<52, 256, 0, stream>>>(A820, 820, tsb, dv820, bu + 3 * H, xcur,
                                   -1, pool_w, pwn, score, keys);
    // up j=0 (n=4096) + output
    k_upmm<<<256, 256, 0, stream>>>(x0, rankb, 820, xcur, Wu + 4 * H * H, tsb, NN);
    k_spmm_out<<<NN, 128, 0, stream>>>(tsb, rp, cols, dinv2, bu + 4 * H, h1,
                                       Wout, dinv1, hbuf, ts2);
    k_gcn_out<<<1024, 256, 0, stream>>>(ts2, rp, cols, dinv1, bout, Fcur, out, step);
  }
}